// Round 16
// baseline (422.298 us; speedup 1.0000x reference)
//
#include <hip/hip_runtime.h>

#define N_NODES 50000
#define N_EDGES 600000
#define HIDDEN 128
#define N_GRAPHS 64
#define SLICES 16
#define SCAN_B ((N_NODES + 255) / 256)   // 196

typedef __attribute__((ext_vector_type(8))) short bf16x8;
typedef __attribute__((ext_vector_type(4))) float f32x4;

__device__ inline ushort f2bf(float v) {
    union { float f; unsigned u; } x; x.f = v;
    unsigned r = (x.u + 0x7FFF + ((x.u >> 16) & 1)) >> 16;  // RNE
    return (ushort)r;
}
__device__ inline float bf2f(ushort h) {
    union { unsigned u; float f; } x; x.u = ((unsigned)h) << 16;
    return x.f;
}

// Feature-chunked layout for node matrices: elem(n,f) at
// ((f>>4) * N_NODES + n) * 16 + (f & 15).

// ---------------- degree ----------------

__global__ void deg_kernel(const int* __restrict__ dst, int* __restrict__ deg) {
    int t = blockIdx.x * 256 + threadIdx.x;
    if (t < N_EDGES) atomicAdd(&deg[dst[t]], 1);
}

// ---------------- 3-pass parallel scan: deg -> rowptr (+ fused dinv) ----------------

__global__ void scan_partial(const int* __restrict__ deg, int* __restrict__ bsum) {
    const int b = blockIdx.x, t = threadIdx.x;
    const int i = b * 256 + t;
    int v = (i < N_NODES) ? deg[i] : 0;
    __shared__ int wsum[4];
#pragma unroll
    for (int o = 32; o > 0; o >>= 1) v += __shfl_down(v, o, 64);
    if ((t & 63) == 0) wsum[t >> 6] = v;
    __syncthreads();
    if (t == 0) bsum[b] = wsum[0] + wsum[1] + wsum[2] + wsum[3];
}

__global__ void scan_bsum(const int* __restrict__ bsum, int* __restrict__ boff,
                          int* __restrict__ rowptr) {
    __shared__ int s[256];
    const int t = threadIdx.x;
    const int v = (t < SCAN_B) ? bsum[t] : 0;
    s[t] = v;
    __syncthreads();
    for (int o = 1; o < 256; o <<= 1) {
        int u = (t >= o) ? s[t - o] : 0;
        __syncthreads();
        s[t] += u;
        __syncthreads();
    }
    if (t < SCAN_B) boff[t] = s[t] - v;      // exclusive
    if (t == 255) rowptr[N_NODES] = s[255];  // total == N_EDGES
}

__global__ void scan_final(const int* __restrict__ deg, const int* __restrict__ boff,
                           int* __restrict__ rowptr, float* __restrict__ dinv) {
    const int b = blockIdx.x, t = threadIdx.x;
    const int i = b * 256 + t;
    __shared__ int s[256];
    const int v = (i < N_NODES) ? deg[i] : 0;
    s[t] = v;
    __syncthreads();
    for (int o = 1; o < 256; o <<= 1) {
        int u = (t >= o) ? s[t - o] : 0;
        __syncthreads();
        s[t] += u;
        __syncthreads();
    }
    if (i < N_NODES) {
        rowptr[i] = boff[b] + s[t] - v;
        dinv[i] = rsqrtf((float)v + 1.0f);
    }
}

// ---------------- CSR fill: interleaved {src, norm} ----------------

__global__ void fill_kernel(const int* __restrict__ src, const int* __restrict__ dst,
                            const int* __restrict__ rowptr, int* __restrict__ fillcnt,
                            const float* __restrict__ dinv, int2* __restrict__ csr) {
    int e = blockIdx.x * 256 + threadIdx.x;
    if (e >= N_EDGES) return;
    const int d = dst[e];
    const int s = src[e];
    const int pos = rowptr[d] + atomicAdd(&fillcnt[d], 1);
    csr[pos] = make_int2(s, __float_as_int(dinv[s] * dinv[d]));
}

// ---------------- W pack: fp32 [128k][128n] -> bf16 hi/lo in MFMA fragment order --

__global__ void pack_w(const float* __restrict__ Wa, const float* __restrict__ Wb,
                       const float* __restrict__ Wc, const float* __restrict__ Wd,
                       ushort* __restrict__ out) {
    const int m = blockIdx.x >> 3;
    const int gid = (blockIdx.x & 7) * 256 + threadIdx.x;  // 0..2047
    const float* W = (m == 0) ? Wa : (m == 1) ? Wb : (m == 2) ? Wc : Wd;
    const int s = gid >> 9;
    const int c = (gid >> 6) & 7;
    const int lane = gid & 63;
    const int kbase = s * 32 + 8 * (lane >> 4);
    const int n = c * 16 + (lane & 15);
    ushort* hi = out + (long)m * 32768;
    ushort* lo = hi + 16384;
#pragma unroll
    for (int j = 0; j < 8; j++) {
        const float v = W[(kbase + j) * HIDDEN + n];
        const ushort h = f2bf(v);
        hi[gid * 8 + j] = h;
        lo[gid * 8 + j] = f2bf(v - bf2f(h));
    }
}

// ---------------- MFMA GEMM: C_chunked = A @ W ; 64-row tile, 256 thr, bf16x3 ----

template <bool CHA, bool BIAS>
__global__ void gemm_mfma(const float* __restrict__ A, const ushort* __restrict__ Wp,
                          float* __restrict__ C, const float* __restrict__ bias,
                          int nrows) {
    __shared__ alignas(16) ushort Ah[64 * 128];
    __shared__ alignas(16) ushort Al[64 * 128];
    const int r0 = blockIdx.x * 64;
    const int tid = threadIdx.x;

#pragma unroll
    for (int i = 0; i < 8; i++) {
        const int idx = tid + i * 256;          // 0..2047 float4 slots
        const int node = idx >> 5;              // 0..63
        float4 v = make_float4(0.f, 0.f, 0.f, 0.f);
        int f0;
        if (CHA) {
            const int c = (idx >> 2) & 7;
            const int f4 = idx & 3;
            f0 = c * 16 + f4 * 4;
            if (r0 + node < nrows)
                v = reinterpret_cast<const float4*>(A)[((long)c * N_NODES + r0 + node) * 4 + f4];
        } else {
            f0 = 4 * (idx & 31);
            if (r0 + node < nrows)
                v = reinterpret_cast<const float4*>(A + (long)r0 * HIDDEN)[idx];
        }
        const ushort h0 = f2bf(v.x), h1 = f2bf(v.y), h2 = f2bf(v.z), h3 = f2bf(v.w);
        ushort4 h4; h4.x = h0; h4.y = h1; h4.z = h2; h4.w = h3;
        ushort4 l4;
        l4.x = f2bf(v.x - bf2f(h0)); l4.y = f2bf(v.y - bf2f(h1));
        l4.z = f2bf(v.z - bf2f(h2)); l4.w = f2bf(v.w - bf2f(h3));
        const int kb = (2 * f0) ^ ((node & 7) << 4);
        *reinterpret_cast<ushort4*>(&Ah[(node * 256 + kb) >> 1]) = h4;
        *reinterpret_cast<ushort4*>(&Al[(node * 256 + kb) >> 1]) = l4;
    }
    __syncthreads();

    const int wave = tid >> 6;
    const int lane = tid & 63;
    const int arow = 16 * wave + (lane & 15);

    f32x4 acc[8];
#pragma unroll
    for (int c = 0; c < 8; c++) acc[c] = (f32x4){0.f, 0.f, 0.f, 0.f};

#pragma unroll
    for (int s = 0; s < 4; s++) {
        const int koff = (s * 64 + ((lane >> 4) << 4)) ^ ((arow & 7) << 4);
        const bf16x8 ahi = *reinterpret_cast<const bf16x8*>(&Ah[(arow * 256 + koff) >> 1]);
        const bf16x8 alo = *reinterpret_cast<const bf16x8*>(&Al[(arow * 256 + koff) >> 1]);
#pragma unroll
        for (int c = 0; c < 8; c++) {
            const bf16x8 bhi = *reinterpret_cast<const bf16x8*>(&Wp[((s * 8 + c) * 64 + lane) * 8]);
            const bf16x8 blo = *reinterpret_cast<const bf16x8*>(&Wp[16384 + ((s * 8 + c) * 64 + lane) * 8]);
            acc[c] = __builtin_amdgcn_mfma_f32_16x16x32_bf16(ahi, bhi, acc[c], 0, 0, 0);
            acc[c] = __builtin_amdgcn_mfma_f32_16x16x32_bf16(alo, bhi, acc[c], 0, 0, 0);
            acc[c] = __builtin_amdgcn_mfma_f32_16x16x32_bf16(ahi, blo, acc[c], 0, 0, 0);
        }
    }

    const int node0 = r0 + 16 * wave + ((lane >> 4) << 2);
    const int fc = lane & 15;
#pragma unroll
    for (int c = 0; c < 8; c++) {
        const float bb = BIAS ? bias[c * 16 + fc] : 0.f;
#pragma unroll
        for (int reg = 0; reg < 4; reg++) {
            const int node = node0 + reg;
            if (node < nrows)
                C[((long)c * N_NODES + node) * 16 + fc] = acc[c][reg] + bb;
        }
    }
}

// ---------------- fused SAGE MFMA GEMM: C = A1@Wl + A2@Wr + b ----------------

__global__ void gemm_sage_mfma(const float* __restrict__ A1, const ushort* __restrict__ Wp1,
                               const float* __restrict__ A2, const ushort* __restrict__ Wp2,
                               const float* __restrict__ bias, float* __restrict__ C,
                               int nrows) {
    __shared__ alignas(16) ushort Ah[64 * 128];
    __shared__ alignas(16) ushort Al[64 * 128];
    const int r0 = blockIdx.x * 64;
    const int tid = threadIdx.x;
    const int wave = tid >> 6;
    const int lane = tid & 63;
    const int arow = 16 * wave + (lane & 15);

    f32x4 acc[8];
#pragma unroll
    for (int c = 0; c < 8; c++) acc[c] = (f32x4){0.f, 0.f, 0.f, 0.f};

    for (int p = 0; p < 2; p++) {
        const float* A = (p == 0) ? A1 : A2;
        const ushort* Wp = (p == 0) ? Wp1 : Wp2;
        if (p) __syncthreads();
#pragma unroll
        for (int i = 0; i < 8; i++) {
            const int idx = tid + i * 256;
            const int node = idx >> 5;
            const int c = (idx >> 2) & 7;
            const int f4 = idx & 3;
            const int f0 = c * 16 + f4 * 4;
            float4 v = make_float4(0.f, 0.f, 0.f, 0.f);
            if (r0 + node < nrows)
                v = reinterpret_cast<const float4*>(A)[((long)c * N_NODES + r0 + node) * 4 + f4];
            const ushort h0 = f2bf(v.x), h1 = f2bf(v.y), h2 = f2bf(v.z), h3 = f2bf(v.w);
            ushort4 h4; h4.x = h0; h4.y = h1; h4.z = h2; h4.w = h3;
            ushort4 l4;
            l4.x = f2bf(v.x - bf2f(h0)); l4.y = f2bf(v.y - bf2f(h1));
            l4.z = f2bf(v.z - bf2f(h2)); l4.w = f2bf(v.w - bf2f(h3));
            const int kb = (2 * f0) ^ ((node & 7) << 4);
            *reinterpret_cast<ushort4*>(&Ah[(node * 256 + kb) >> 1]) = h4;
            *reinterpret_cast<ushort4*>(&Al[(node * 256 + kb) >> 1]) = l4;
        }
        __syncthreads();

#pragma unroll
        for (int s = 0; s < 4; s++) {
            const int koff = (s * 64 + ((lane >> 4) << 4)) ^ ((arow & 7) << 4);
            const bf16x8 ahi = *reinterpret_cast<const bf16x8*>(&Ah[(arow * 256 + koff) >> 1]);
            const bf16x8 alo = *reinterpret_cast<const bf16x8*>(&Al[(arow * 256 + koff) >> 1]);
#pragma unroll
            for (int c = 0; c < 8; c++) {
                const bf16x8 bhi = *reinterpret_cast<const bf16x8*>(&Wp[((s * 8 + c) * 64 + lane) * 8]);
                const bf16x8 blo = *reinterpret_cast<const bf16x8*>(&Wp[16384 + ((s * 8 + c) * 64 + lane) * 8]);
                acc[c] = __builtin_amdgcn_mfma_f32_16x16x32_bf16(ahi, bhi, acc[c], 0, 0, 0);
                acc[c] = __builtin_amdgcn_mfma_f32_16x16x32_bf16(alo, bhi, acc[c], 0, 0, 0);
                acc[c] = __builtin_amdgcn_mfma_f32_16x16x32_bf16(ahi, blo, acc[c], 0, 0, 0);
            }
        }
    }

    const int node0 = r0 + 16 * wave + ((lane >> 4) << 2);
    const int fc = lane & 15;
#pragma unroll
    for (int c = 0; c < 8; c++) {
        const float bb = bias[c * 16 + fc];
#pragma unroll
        for (int reg = 0; reg < 4; reg++) {
            const int node = node0 + reg;
            if (node < nrows)
                C[((long)c * N_NODES + node) * 16 + fc] = acc[c][reg] + bb;
        }
    }
}

// ---------------- GCN gather (full-row float4): out = relu(sum h[s]*n + h[d]/deg + b)
// wave = 2 nodes x 32 lanes; lane l: chunk=l>>2, f4=l&3 -> one float4 of the row.
// CSR loop runs ONCE per node (vs once per chunk-block before).

__global__ void gather_gcn(const float* __restrict__ h, const int* __restrict__ rowptr,
                           const int2* __restrict__ csr, const float* __restrict__ dinv,
                           const float* __restrict__ bias, float* __restrict__ out) {
    const int tid = threadIdx.x;
    const int d = blockIdx.x * 8 + (tid >> 5);
    if (d >= N_NODES) return;
    const int l = tid & 31;
    const long cbase = (long)(l >> 2) * N_NODES;
    const int fo = (l & 3) * 4;
    const float di = dinv[d];
    const int beg = rowptr[d];
    const int end = rowptr[d + 1];
    float ax = 0.f, ay = 0.f, az = 0.f, aw = 0.f;
    int j = beg;
    for (; j + 2 <= end; j += 2) {
        const int2 e0 = csr[j];
        const int2 e1 = csr[j + 1];
        const float n0 = __int_as_float(e0.y);
        const float n1 = __int_as_float(e1.y);
        const float4 v0 = *reinterpret_cast<const float4*>(h + (cbase + e0.x) * 16 + fo);
        const float4 v1 = *reinterpret_cast<const float4*>(h + (cbase + e1.x) * 16 + fo);
        ax += v0.x * n0 + v1.x * n1;
        ay += v0.y * n0 + v1.y * n1;
        az += v0.z * n0 + v1.z * n1;
        aw += v0.w * n0 + v1.w * n1;
    }
    if (j < end) {
        const int2 e0 = csr[j];
        const float n0 = __int_as_float(e0.y);
        const float4 v0 = *reinterpret_cast<const float4*>(h + (cbase + e0.x) * 16 + fo);
        ax += v0.x * n0;
        ay += v0.y * n0;
        az += v0.z * n0;
        aw += v0.w * n0;
    }
    const float4 hv = *reinterpret_cast<const float4*>(h + (cbase + d) * 16 + fo);
    const float4 b = *reinterpret_cast<const float4*>(bias + (l >> 2) * 16 + fo);
    const float invdeg = di * di;
    float4 res;
    res.x = fmaxf(ax + hv.x * invdeg + b.x, 0.f);
    res.y = fmaxf(ay + hv.y * invdeg + b.y, 0.f);
    res.z = fmaxf(az + hv.z * invdeg + b.z, 0.f);
    res.w = fmaxf(aw + hv.w * invdeg + b.w, 0.f);
    *reinterpret_cast<float4*>(out + (cbase + d) * 16 + fo) = res;
}

// ---------------- SAGE mean gather (full-row float4) ----------------

__global__ void gather_sage(const float* __restrict__ h, const int* __restrict__ rowptr,
                            const int2* __restrict__ csr, float* __restrict__ mean) {
    const int tid = threadIdx.x;
    const int d = blockIdx.x * 8 + (tid >> 5);
    if (d >= N_NODES) return;
    const int l = tid & 31;
    const long cbase = (long)(l >> 2) * N_NODES;
    const int fo = (l & 3) * 4;
    const int beg = rowptr[d];
    const int end = rowptr[d + 1];
    float ax = 0.f, ay = 0.f, az = 0.f, aw = 0.f;
    int j = beg;
    for (; j + 2 <= end; j += 2) {
        const int2 e0 = csr[j];
        const int2 e1 = csr[j + 1];
        const float4 v0 = *reinterpret_cast<const float4*>(h + (cbase + e0.x) * 16 + fo);
        const float4 v1 = *reinterpret_cast<const float4*>(h + (cbase + e1.x) * 16 + fo);
        ax += v0.x + v1.x;
        ay += v0.y + v1.y;
        az += v0.z + v1.z;
        aw += v0.w + v1.w;
    }
    if (j < end) {
        const int2 e0 = csr[j];
        const float4 v0 = *reinterpret_cast<const float4*>(h + (cbase + e0.x) * 16 + fo);
        ax += v0.x;
        ay += v0.y;
        az += v0.z;
        aw += v0.w;
    }
    const float inv = 1.0f / fmaxf((float)(end - beg), 1.0f);
    float4 res;
    res.x = ax * inv;
    res.y = ay * inv;
    res.z = az * inv;
    res.w = aw * inv;
    *reinterpret_cast<float4*>(mean + (cbase + d) * 16 + fo) = res;
}

// ---------------- pooling (two-stage; batch sorted; node input chunked) ---------

__device__ int lower_bound_batch(const int* __restrict__ batch, int key) {
    int lo = 0, hi = N_NODES;
    while (lo < hi) {
        int mid = (lo + hi) >> 1;
        if (batch[mid] < key) lo = mid + 1;
        else hi = mid;
    }
    return lo;
}

__global__ void pool_partial(const float* __restrict__ node, const int* __restrict__ batch,
                             float* __restrict__ part) {
    const int b = blockIdx.x;          // g * SLICES + k
    const int g = b / SLICES;
    const int k = b % SLICES;
    const int t = threadIdx.x;         // feature t
    const long cbase = (long)(t >> 4) * N_NODES;
    const int foff = t & 15;
    const int lo = lower_bound_batch(batch, g);
    const int hi = lower_bound_batch(batch, g + 1);
    const int len = hi - lo;
    const int per = (len + SLICES - 1) / SLICES;
    const int s = lo + k * per;
    const int e = min(s + per, hi);
    float acc = 0.f;
    for (int i = s; i < e; i++) acc += node[(cbase + i) * 16 + foff];
    part[(long)b * HIDDEN + t] = acc;
}

__global__ void pool_reduce(const float* __restrict__ part, const int* __restrict__ batch,
                            float* __restrict__ out) {
    const int g = blockIdx.x;
    const int t = threadIdx.x;
    float acc = 0.f;
#pragma unroll
    for (int k = 0; k < SLICES; k++) acc += part[(long)(g * SLICES + k) * HIDDEN + t];
    const int lo = lower_bound_batch(batch, g);
    const int hi = lower_bound_batch(batch, g + 1);
    out[g * HIDDEN + t] = acc / fmaxf((float)(hi - lo), 1.0f);
}

// ---------------- launch ----------------

extern "C" void kernel_launch(void* const* d_in, const int* in_sizes, int n_in,
                              void* d_out, int out_size, void* d_ws, size_t ws_size,
                              hipStream_t stream) {
    const float* x    = (const float*)d_in[0];
    const int*   ei   = (const int*)d_in[1];   // [2][E]
    const int*   batch= (const int*)d_in[2];
    const float* W1   = (const float*)d_in[3];
    const float* b1   = (const float*)d_in[4];
    const float* W2   = (const float*)d_in[5];
    const float* b2   = (const float*)d_in[6];
    const float* W_l  = (const float*)d_in[7];
    const float* W_r  = (const float*)d_in[8];
    const float* b_s  = (const float*)d_in[9];
    float* out = (float*)d_out;

    const int* src = ei;
    const int* dst = ei + N_EDGES;

    // workspace layout
    char* ws = (char*)d_ws;
    const size_t NB = (size_t)N_NODES * HIDDEN * sizeof(float);  // 25.6 MB
    float* B1 = (float*)(ws);                    // h buffer (chunked)
    float* B2 = (float*)(ws + NB);               // mean buffer (chunked)
    float* B3 = (float*)(ws + 2 * NB);           // layer output (chunked)
    size_t off = 3 * NB;
    int*   deg      = (int*)(ws + off);   off += (size_t)N_NODES * 4;
    float* dinv     = (float*)(ws + off); off += (size_t)N_NODES * 4;
    int*   rowptr   = (int*)(ws + off);   off += (size_t)(N_NODES + 1) * 4;
    int*   fillcnt  = (int*)(ws + off);   off += (size_t)N_NODES * 4;
    int2*  csr      = (int2*)(ws + off);  off += (size_t)N_EDGES * 8;
    float* part     = (float*)(ws + off); off += (size_t)N_GRAPHS * SLICES * HIDDEN * 4;
    int*   bsum     = (int*)(ws + off);   off += (size_t)SCAN_B * 4;
    int*   boff     = (int*)(ws + off);   off += (size_t)SCAN_B * 4;
    ushort* wpack   = (ushort*)(ws + off); off += (size_t)4 * 32768 * 2;  // 4 x (hi16K+lo16K)

    const ushort* Wp1 = wpack;                // W1
    const ushort* Wp2 = wpack + 32768;        // W2
    const ushort* WpL = wpack + 2 * 32768;    // W_l
    const ushort* WpR = wpack + 3 * 32768;    // W_r

    const int EB = (N_EDGES + 255) / 256;
    const int GB = (N_NODES + 63) / 64;   // 64-row MFMA tiles (782)
    const int GTB = (N_NODES + 7) / 8;    // gather blocks (8 nodes/block)

    // ---- pack weights (bf16 hi/lo, fragment order) ----
    pack_w<<<32, 256, 0, stream>>>(W1, W2, W_l, W_r, wpack);

    // ---- build CSR (once per call) ----
    hipMemsetAsync(deg, 0, (size_t)N_NODES * 4, stream);
    hipMemsetAsync(fillcnt, 0, (size_t)N_NODES * 4, stream);
    deg_kernel<<<EB, 256, 0, stream>>>(dst, deg);
    scan_partial<<<SCAN_B, 256, 0, stream>>>(deg, bsum);
    scan_bsum<<<1, 256, 0, stream>>>(bsum, boff, rowptr);
    scan_final<<<SCAN_B, 256, 0, stream>>>(deg, boff, rowptr, dinv);
    fill_kernel<<<EB, 256, 0, stream>>>(src, dst, rowptr, fillcnt, dinv, csr);

    // ---- GCN layer 1 ----
    gemm_mfma<false, false><<<GB, 256, 0, stream>>>(x, Wp1, B1, nullptr, N_NODES);
    gather_gcn<<<GTB, 256, 0, stream>>>(B1, rowptr, csr, dinv, b1, B3);

    // ---- GCN layer 2 ----
    gemm_mfma<true, false><<<GB, 256, 0, stream>>>(B3, Wp2, B1, nullptr, N_NODES);
    gather_gcn<<<GTB, 256, 0, stream>>>(B1, rowptr, csr, dinv, b2, B3);

    // ---- SAGE ----
    gather_sage<<<GTB, 256, 0, stream>>>(B3, rowptr, csr, B2);
    gemm_sage_mfma<<<GB, 256, 0, stream>>>(B2, WpL, B3, WpR, b_s, B1, N_NODES);

    // ---- global mean pool (two-stage, no atomics) ----
    pool_partial<<<N_GRAPHS * SLICES, 128, 0, stream>>>(B1, batch, part);
    pool_reduce<<<N_GRAPHS, 128, 0, stream>>>(part, batch, out);
}

// Round 18
// 269.636 us; speedup vs baseline: 1.5662x; 1.5662x over previous
//
#include <hip/hip_runtime.h>

#define N_NODES 50000
#define N_EDGES 600000
#define HIDDEN 128
#define N_GRAPHS 64
#define SLICES 16
#define SCAN_B ((N_NODES + 255) / 256)   // 196

typedef __attribute__((ext_vector_type(8))) short bf16x8;
typedef __attribute__((ext_vector_type(4))) float f32x4;

__device__ inline ushort f2bf(float v) {
    union { float f; unsigned u; } x; x.f = v;
    unsigned r = (x.u + 0x7FFF + ((x.u >> 16) & 1)) >> 16;  // RNE
    return (ushort)r;
}
__device__ inline float bf2f(ushort h) {
    union { unsigned u; float f; } x; x.u = ((unsigned)h) << 16;
    return x.f;
}

// fp32 node matrices use feature-chunked layout: elem(n,f) at
// ((f>>4)*N + n)*16 + (f&15).  bf16 copies are ROW-MAJOR (256B rows, 2 lines).

// ---------------- degree ----------------

__global__ void deg_kernel(const int* __restrict__ dst, int* __restrict__ deg) {
    int t = blockIdx.x * 256 + threadIdx.x;
    if (t < N_EDGES) atomicAdd(&deg[dst[t]], 1);
}

// ---------------- 3-pass parallel scan: deg -> rowptr (+ fused dinv) ----------------

__global__ void scan_partial(const int* __restrict__ deg, int* __restrict__ bsum) {
    const int b = blockIdx.x, t = threadIdx.x;
    const int i = b * 256 + t;
    int v = (i < N_NODES) ? deg[i] : 0;
    __shared__ int wsum[4];
#pragma unroll
    for (int o = 32; o > 0; o >>= 1) v += __shfl_down(v, o, 64);
    if ((t & 63) == 0) wsum[t >> 6] = v;
    __syncthreads();
    if (t == 0) bsum[b] = wsum[0] + wsum[1] + wsum[2] + wsum[3];
}

__global__ void scan_bsum(const int* __restrict__ bsum, int* __restrict__ boff,
                          int* __restrict__ rowptr) {
    __shared__ int s[256];
    const int t = threadIdx.x;
    const int v = (t < SCAN_B) ? bsum[t] : 0;
    s[t] = v;
    __syncthreads();
    for (int o = 1; o < 256; o <<= 1) {
        int u = (t >= o) ? s[t - o] : 0;
        __syncthreads();
        s[t] += u;
        __syncthreads();
    }
    if (t < SCAN_B) boff[t] = s[t] - v;      // exclusive
    if (t == 255) rowptr[N_NODES] = s[255];  // total == N_EDGES
}

__global__ void scan_final(const int* __restrict__ deg, const int* __restrict__ boff,
                           int* __restrict__ rowptr, float* __restrict__ dinv) {
    const int b = blockIdx.x, t = threadIdx.x;
    const int i = b * 256 + t;
    __shared__ int s[256];
    const int v = (i < N_NODES) ? deg[i] : 0;
    s[t] = v;
    __syncthreads();
    for (int o = 1; o < 256; o <<= 1) {
        int u = (t >= o) ? s[t - o] : 0;
        __syncthreads();
        s[t] += u;
        __syncthreads();
    }
    if (i < N_NODES) {
        rowptr[i] = boff[b] + s[t] - v;
        dinv[i] = rsqrtf((float)v + 1.0f);
    }
}

// ---------------- CSR fill: interleaved {src, norm} ----------------

__global__ void fill_kernel(const int* __restrict__ src, const int* __restrict__ dst,
                            const int* __restrict__ rowptr, int* __restrict__ fillcnt,
                            const float* __restrict__ dinv, int2* __restrict__ csr) {
    int e = blockIdx.x * 256 + threadIdx.x;
    if (e >= N_EDGES) return;
    const int d = dst[e];
    const int s = src[e];
    const int pos = rowptr[d] + atomicAdd(&fillcnt[d], 1);
    csr[pos] = make_int2(s, __float_as_int(dinv[s] * dinv[d]));
}

// ---------------- W pack: fp32 [128k][128n] -> bf16 hi/lo in MFMA fragment order --

__global__ void pack_w(const float* __restrict__ Wa, const float* __restrict__ Wb,
                       const float* __restrict__ Wc, const float* __restrict__ Wd,
                       ushort* __restrict__ out) {
    const int m = blockIdx.x >> 3;
    const int gid = (blockIdx.x & 7) * 256 + threadIdx.x;  // 0..2047
    const float* W = (m == 0) ? Wa : (m == 1) ? Wb : (m == 2) ? Wc : Wd;
    const int s = gid >> 9;
    const int c = (gid >> 6) & 7;
    const int lane = gid & 63;
    const int kbase = s * 32 + 8 * (lane >> 4);
    const int n = c * 16 + (lane & 15);
    ushort* hi = out + (long)m * 32768;
    ushort* lo = hi + 16384;
#pragma unroll
    for (int j = 0; j < 8; j++) {
        const float v = W[(kbase + j) * HIDDEN + n];
        const ushort h = f2bf(v);
        hi[gid * 8 + j] = h;
        lo[gid * 8 + j] = f2bf(v - bf2f(h));
    }
}

// ---------------- MFMA GEMM: Cb_bf16rows = A @ W ; 64-row tile, bf16x3 ----------
// CHA: A feature-chunked fp32; else row-major fp32. Output: bf16 ROW-MAJOR
// (consumed only by gathers). No bias (GCN bias fused into gather).

template <bool CHA>
__global__ void gemm_mfma(const float* __restrict__ A, const ushort* __restrict__ Wp,
                          ushort* __restrict__ Cb, int nrows) {
    __shared__ alignas(16) ushort Ah[64 * 128];
    __shared__ alignas(16) ushort Al[64 * 128];
    const int r0 = blockIdx.x * 64;
    const int tid = threadIdx.x;

#pragma unroll
    for (int i = 0; i < 8; i++) {
        const int idx = tid + i * 256;          // 0..2047 float4 slots
        const int node = idx >> 5;              // 0..63
        float4 v = make_float4(0.f, 0.f, 0.f, 0.f);
        int f0;
        if (CHA) {
            const int c = (idx >> 2) & 7;
            const int f4 = idx & 3;
            f0 = c * 16 + f4 * 4;
            if (r0 + node < nrows)
                v = reinterpret_cast<const float4*>(A)[((long)c * N_NODES + r0 + node) * 4 + f4];
        } else {
            f0 = 4 * (idx & 31);
            if (r0 + node < nrows)
                v = reinterpret_cast<const float4*>(A + (long)r0 * HIDDEN)[idx];
        }
        const ushort h0 = f2bf(v.x), h1 = f2bf(v.y), h2 = f2bf(v.z), h3 = f2bf(v.w);
        ushort4 h4; h4.x = h0; h4.y = h1; h4.z = h2; h4.w = h3;
        ushort4 l4;
        l4.x = f2bf(v.x - bf2f(h0)); l4.y = f2bf(v.y - bf2f(h1));
        l4.z = f2bf(v.z - bf2f(h2)); l4.w = f2bf(v.w - bf2f(h3));
        const int kb = (2 * f0) ^ ((node & 7) << 4);
        *reinterpret_cast<ushort4*>(&Ah[(node * 256 + kb) >> 1]) = h4;
        *reinterpret_cast<ushort4*>(&Al[(node * 256 + kb) >> 1]) = l4;
    }
    __syncthreads();

    const int wave = tid >> 6;
    const int lane = tid & 63;
    const int arow = 16 * wave + (lane & 15);

    f32x4 acc[8];
#pragma unroll
    for (int c = 0; c < 8; c++) acc[c] = (f32x4){0.f, 0.f, 0.f, 0.f};

#pragma unroll
    for (int s = 0; s < 4; s++) {
        const int koff = (s * 64 + ((lane >> 4) << 4)) ^ ((arow & 7) << 4);
        const bf16x8 ahi = *reinterpret_cast<const bf16x8*>(&Ah[(arow * 256 + koff) >> 1]);
        const bf16x8 alo = *reinterpret_cast<const bf16x8*>(&Al[(arow * 256 + koff) >> 1]);
#pragma unroll
        for (int c = 0; c < 8; c++) {
            const bf16x8 bhi = *reinterpret_cast<const bf16x8*>(&Wp[((s * 8 + c) * 64 + lane) * 8]);
            const bf16x8 blo = *reinterpret_cast<const bf16x8*>(&Wp[16384 + ((s * 8 + c) * 64 + lane) * 8]);
            acc[c] = __builtin_amdgcn_mfma_f32_16x16x32_bf16(ahi, bhi, acc[c], 0, 0, 0);
            acc[c] = __builtin_amdgcn_mfma_f32_16x16x32_bf16(alo, bhi, acc[c], 0, 0, 0);
            acc[c] = __builtin_amdgcn_mfma_f32_16x16x32_bf16(ahi, blo, acc[c], 0, 0, 0);
        }
    }

    const int node0 = r0 + 16 * wave + ((lane >> 4) << 2);
    const int fc = lane & 15;
#pragma unroll
    for (int c = 0; c < 8; c++) {
#pragma unroll
        for (int reg = 0; reg < 4; reg++) {
            const int node = node0 + reg;
            if (node < nrows)
                Cb[(long)node * HIDDEN + c * 16 + fc] = f2bf(acc[c][reg]);
        }
    }
}

// ---------------- fused SAGE MFMA GEMM: C_chunked_fp32 = A1@Wl + A2@Wr + b -------

__global__ void gemm_sage_mfma(const float* __restrict__ A1, const ushort* __restrict__ Wp1,
                               const float* __restrict__ A2, const ushort* __restrict__ Wp2,
                               const float* __restrict__ bias, float* __restrict__ C,
                               int nrows) {
    __shared__ alignas(16) ushort Ah[64 * 128];
    __shared__ alignas(16) ushort Al[64 * 128];
    const int r0 = blockIdx.x * 64;
    const int tid = threadIdx.x;
    const int wave = tid >> 6;
    const int lane = tid & 63;
    const int arow = 16 * wave + (lane & 15);

    f32x4 acc[8];
#pragma unroll
    for (int c = 0; c < 8; c++) acc[c] = (f32x4){0.f, 0.f, 0.f, 0.f};

    for (int p = 0; p < 2; p++) {
        const float* A = (p == 0) ? A1 : A2;
        const ushort* Wp = (p == 0) ? Wp1 : Wp2;
        if (p) __syncthreads();
#pragma unroll
        for (int i = 0; i < 8; i++) {
            const int idx = tid + i * 256;
            const int node = idx >> 5;
            const int c = (idx >> 2) & 7;
            const int f4 = idx & 3;
            const int f0 = c * 16 + f4 * 4;
            float4 v = make_float4(0.f, 0.f, 0.f, 0.f);
            if (r0 + node < nrows)
                v = reinterpret_cast<const float4*>(A)[((long)c * N_NODES + r0 + node) * 4 + f4];
            const ushort h0 = f2bf(v.x), h1 = f2bf(v.y), h2 = f2bf(v.z), h3 = f2bf(v.w);
            ushort4 h4; h4.x = h0; h4.y = h1; h4.z = h2; h4.w = h3;
            ushort4 l4;
            l4.x = f2bf(v.x - bf2f(h0)); l4.y = f2bf(v.y - bf2f(h1));
            l4.z = f2bf(v.z - bf2f(h2)); l4.w = f2bf(v.w - bf2f(h3));
            const int kb = (2 * f0) ^ ((node & 7) << 4);
            *reinterpret_cast<ushort4*>(&Ah[(node * 256 + kb) >> 1]) = h4;
            *reinterpret_cast<ushort4*>(&Al[(node * 256 + kb) >> 1]) = l4;
        }
        __syncthreads();

#pragma unroll
        for (int s = 0; s < 4; s++) {
            const int koff = (s * 64 + ((lane >> 4) << 4)) ^ ((arow & 7) << 4);
            const bf16x8 ahi = *reinterpret_cast<const bf16x8*>(&Ah[(arow * 256 + koff) >> 1]);
            const bf16x8 alo = *reinterpret_cast<const bf16x8*>(&Al[(arow * 256 + koff) >> 1]);
#pragma unroll
            for (int c = 0; c < 8; c++) {
                const bf16x8 bhi = *reinterpret_cast<const bf16x8*>(&Wp[((s * 8 + c) * 64 + lane) * 8]);
                const bf16x8 blo = *reinterpret_cast<const bf16x8*>(&Wp[16384 + ((s * 8 + c) * 64 + lane) * 8]);
                acc[c] = __builtin_amdgcn_mfma_f32_16x16x32_bf16(ahi, bhi, acc[c], 0, 0, 0);
                acc[c] = __builtin_amdgcn_mfma_f32_16x16x32_bf16(alo, bhi, acc[c], 0, 0, 0);
                acc[c] = __builtin_amdgcn_mfma_f32_16x16x32_bf16(ahi, blo, acc[c], 0, 0, 0);
            }
        }
    }

    const int node0 = r0 + 16 * wave + ((lane >> 4) << 2);
    const int fc = lane & 15;
#pragma unroll
    for (int c = 0; c < 8; c++) {
        const float bb = bias[c * 16 + fc];
#pragma unroll
        for (int reg = 0; reg < 4; reg++) {
            const int node = node0 + reg;
            if (node < nrows)
                C[((long)c * N_NODES + node) * 16 + fc] = acc[c][reg] + bb;
        }
    }
}

// ---------------- GCN gather (bf16 row-major input, full row, loop once/node) ----
// wave = 2 nodes x 32 lanes; lane l reads bf16x4 at byte offset l*8 of 256B row.
// Output: fp32 chunked (for next GEMM); optional bf16 row copy (for SAGE).

template <bool WB16>
__global__ void gather_gcn(const ushort* __restrict__ hb, const int* __restrict__ rowptr,
                           const int2* __restrict__ csr, const float* __restrict__ dinv,
                           const float* __restrict__ bias, float* __restrict__ outC,
                           ushort* __restrict__ outB) {
    const int tid = threadIdx.x;
    const int d = blockIdx.x * 8 + (tid >> 5);
    if (d >= N_NODES) return;
    const int l = tid & 31;
    const float di = dinv[d];
    const int beg = rowptr[d];
    const int end = rowptr[d + 1];
    float a0 = 0.f, a1 = 0.f, a2 = 0.f, a3 = 0.f;
    int j = beg;
    for (; j + 2 <= end; j += 2) {
        const int2 e0 = csr[j];
        const int2 e1 = csr[j + 1];
        const float n0 = __int_as_float(e0.y);
        const float n1 = __int_as_float(e1.y);
        const ushort4 u0 = *reinterpret_cast<const ushort4*>(hb + (long)e0.x * HIDDEN + l * 4);
        const ushort4 u1 = *reinterpret_cast<const ushort4*>(hb + (long)e1.x * HIDDEN + l * 4);
        a0 += bf2f(u0.x) * n0 + bf2f(u1.x) * n1;
        a1 += bf2f(u0.y) * n0 + bf2f(u1.y) * n1;
        a2 += bf2f(u0.z) * n0 + bf2f(u1.z) * n1;
        a3 += bf2f(u0.w) * n0 + bf2f(u1.w) * n1;
    }
    if (j < end) {
        const int2 e0 = csr[j];
        const float n0 = __int_as_float(e0.y);
        const ushort4 u0 = *reinterpret_cast<const ushort4*>(hb + (long)e0.x * HIDDEN + l * 4);
        a0 += bf2f(u0.x) * n0;
        a1 += bf2f(u0.y) * n0;
        a2 += bf2f(u0.z) * n0;
        a3 += bf2f(u0.w) * n0;
    }
    const ushort4 us = *reinterpret_cast<const ushort4*>(hb + (long)d * HIDDEN + l * 4);
    const float4 b = *reinterpret_cast<const float4*>(bias + l * 4);
    const float invdeg = di * di;
    float4 res;
    res.x = fmaxf(a0 + bf2f(us.x) * invdeg + b.x, 0.f);
    res.y = fmaxf(a1 + bf2f(us.y) * invdeg + b.y, 0.f);
    res.z = fmaxf(a2 + bf2f(us.z) * invdeg + b.z, 0.f);
    res.w = fmaxf(a3 + bf2f(us.w) * invdeg + b.w, 0.f);
    // fp32 chunked write: feature f = l*4+k -> chunk l>>2, within (l&3)*4+k
    *reinterpret_cast<float4*>(outC + ((long)(l >> 2) * N_NODES + d) * 16 + (l & 3) * 4) = res;
    if (WB16) {
        ushort4 o;
        o.x = f2bf(res.x); o.y = f2bf(res.y); o.z = f2bf(res.z); o.w = f2bf(res.w);
        *reinterpret_cast<ushort4*>(outB + (long)d * HIDDEN + l * 4) = o;
    }
}

// ---------------- SAGE mean gather (bf16 rows in, fp32 chunked out) -------------

__global__ void gather_sage(const ushort* __restrict__ hb, const int* __restrict__ rowptr,
                            const int2* __restrict__ csr, float* __restrict__ mean) {
    const int tid = threadIdx.x;
    const int d = blockIdx.x * 8 + (tid >> 5);
    if (d >= N_NODES) return;
    const int l = tid & 31;
    const int beg = rowptr[d];
    const int end = rowptr[d + 1];
    float a0 = 0.f, a1 = 0.f, a2 = 0.f, a3 = 0.f;
    int j = beg;
    for (; j + 2 <= end; j += 2) {
        const int2 e0 = csr[j];
        const int2 e1 = csr[j + 1];
        const ushort4 u0 = *reinterpret_cast<const ushort4*>(hb + (long)e0.x * HIDDEN + l * 4);
        const ushort4 u1 = *reinterpret_cast<const ushort4*>(hb + (long)e1.x * HIDDEN + l * 4);
        a0 += bf2f(u0.x) + bf2f(u1.x);
        a1 += bf2f(u0.y) + bf2f(u1.y);
        a2 += bf2f(u0.z) + bf2f(u1.z);
        a3 += bf2f(u0.w) + bf2f(u1.w);
    }
    if (j < end) {
        const int2 e0 = csr[j];
        const ushort4 u0 = *reinterpret_cast<const ushort4*>(hb + (long)e0.x * HIDDEN + l * 4);
        a0 += bf2f(u0.x);
        a1 += bf2f(u0.y);
        a2 += bf2f(u0.z);
        a3 += bf2f(u0.w);
    }
    const float inv = 1.0f / fmaxf((float)(end - beg), 1.0f);
    float4 res;
    res.x = a0 * inv; res.y = a1 * inv; res.z = a2 * inv; res.w = a3 * inv;
    *reinterpret_cast<float4*>(mean + ((long)(l >> 2) * N_NODES + d) * 16 + (l & 3) * 4) = res;
}

// ---------------- pooling (two-stage; batch sorted; node input chunked) ---------

__device__ int lower_bound_batch(const int* __restrict__ batch, int key) {
    int lo = 0, hi = N_NODES;
    while (lo < hi) {
        int mid = (lo + hi) >> 1;
        if (batch[mid] < key) lo = mid + 1;
        else hi = mid;
    }
    return lo;
}

__global__ void pool_partial(const float* __restrict__ node, const int* __restrict__ batch,
                             float* __restrict__ part) {
    const int b = blockIdx.x;          // g * SLICES + k
    const int g = b / SLICES;
    const int k = b % SLICES;
    const int t = threadIdx.x;         // feature t
    const long cbase = (long)(t >> 4) * N_NODES;
    const int foff = t & 15;
    const int lo = lower_bound_batch(batch, g);
    const int hi = lower_bound_batch(batch, g + 1);
    const int len = hi - lo;
    const int per = (len + SLICES - 1) / SLICES;
    const int s = lo + k * per;
    const int e = min(s + per, hi);
    float acc = 0.f;
    for (int i = s; i < e; i++) acc += node[(cbase + i) * 16 + foff];
    part[(long)b * HIDDEN + t] = acc;
}

__global__ void pool_reduce(const float* __restrict__ part, const int* __restrict__ batch,
                            float* __restrict__ out) {
    const int g = blockIdx.x;
    const int t = threadIdx.x;
    float acc = 0.f;
#pragma unroll
    for (int k = 0; k < SLICES; k++) acc += part[(long)(g * SLICES + k) * HIDDEN + t];
    const int lo = lower_bound_batch(batch, g);
    const int hi = lower_bound_batch(batch, g + 1);
    out[g * HIDDEN + t] = acc / fmaxf((float)(hi - lo), 1.0f);
}

// ---------------- launch ----------------

extern "C" void kernel_launch(void* const* d_in, const int* in_sizes, int n_in,
                              void* d_out, int out_size, void* d_ws, size_t ws_size,
                              hipStream_t stream) {
    const float* x    = (const float*)d_in[0];
    const int*   ei   = (const int*)d_in[1];   // [2][E]
    const int*   batch= (const int*)d_in[2];
    const float* W1   = (const float*)d_in[3];
    const float* b1   = (const float*)d_in[4];
    const float* W2   = (const float*)d_in[5];
    const float* b2   = (const float*)d_in[6];
    const float* W_l  = (const float*)d_in[7];
    const float* W_r  = (const float*)d_in[8];
    const float* b_s  = (const float*)d_in[9];
    float* out = (float*)d_out;

    const int* src = ei;
    const int* dst = ei + N_EDGES;

    // workspace layout (bf16 row buffers alias fp32 buffers with disjoint lifetimes)
    char* ws = (char*)d_ws;
    const size_t NB = (size_t)N_NODES * HIDDEN * sizeof(float);  // 25.6 MB
    float* B1 = (float*)(ws);                    // fp32 chunked (h1, then sage out)
    float* B2 = (float*)(ws + NB);               // fp32 chunked (sage mean)
    float* B3 = (float*)(ws + 2 * NB);           // fp32 chunked (h2)
    ushort* HB1 = (ushort*)B2;                   // bf16 rows: h_pre (gemm1/2 out)
    ushort* HB2 = (ushort*)B1;                   // bf16 rows: h2 copy
    size_t off = 3 * NB;
    int*   deg      = (int*)(ws + off);   off += (size_t)N_NODES * 4;
    float* dinv     = (float*)(ws + off); off += (size_t)N_NODES * 4;
    int*   rowptr   = (int*)(ws + off);   off += (size_t)(N_NODES + 1) * 4;
    int*   fillcnt  = (int*)(ws + off);   off += (size_t)N_NODES * 4;
    int2*  csr      = (int2*)(ws + off);  off += (size_t)N_EDGES * 8;
    float* part     = (float*)(ws + off); off += (size_t)N_GRAPHS * SLICES * HIDDEN * 4;
    int*   bsum     = (int*)(ws + off);   off += (size_t)SCAN_B * 4;
    int*   boff     = (int*)(ws + off);   off += (size_t)SCAN_B * 4;
    ushort* wpack   = (ushort*)(ws + off); off += (size_t)4 * 32768 * 2;

    const ushort* Wp1 = wpack;                // W1
    const ushort* Wp2 = wpack + 32768;        // W2
    const ushort* WpL = wpack + 2 * 32768;    // W_l
    const ushort* WpR = wpack + 3 * 32768;    // W_r

    const int EB = (N_EDGES + 255) / 256;
    const int GB = (N_NODES + 63) / 64;   // 64-row MFMA tiles (782)
    const int GTB = (N_NODES + 7) / 8;    // gather blocks (8 nodes/block)

    // ---- pack weights (bf16 hi/lo, fragment order) ----
    pack_w<<<32, 256, 0, stream>>>(W1, W2, W_l, W_r, wpack);

    // ---- build CSR (once per call) ----
    hipMemsetAsync(deg, 0, (size_t)N_NODES * 4, stream);
    hipMemsetAsync(fillcnt, 0, (size_t)N_NODES * 4, stream);
    deg_kernel<<<EB, 256, 0, stream>>>(dst, deg);
    scan_partial<<<SCAN_B, 256, 0, stream>>>(deg, bsum);
    scan_bsum<<<1, 256, 0, stream>>>(bsum, boff, rowptr);
    scan_final<<<SCAN_B, 256, 0, stream>>>(deg, boff, rowptr, dinv);
    fill_kernel<<<EB, 256, 0, stream>>>(src, dst, rowptr, fillcnt, dinv, csr);

    // ---- GCN layer 1: h1_pre(bf16 rows) -> h1(fp32 chunked) ----
    gemm_mfma<false><<<GB, 256, 0, stream>>>(x, Wp1, HB1, N_NODES);
    gather_gcn<false><<<GTB, 256, 0, stream>>>(HB1, rowptr, csr, dinv, b1, B1, nullptr);

    // ---- GCN layer 2: h2_pre(bf16 rows) -> h2(fp32 chunked + bf16 rows) ----
    gemm_mfma<true><<<GB, 256, 0, stream>>>(B1, Wp2, HB1, N_NODES);
    gather_gcn<true><<<GTB, 256, 0, stream>>>(HB1, rowptr, csr, dinv, b2, B3, HB2);

    // ---- SAGE ----
    gather_sage<<<GTB, 256, 0, stream>>>(HB2, rowptr, csr, B2);
    gemm_sage_mfma<<<GB, 256, 0, stream>>>(B2, WpL, B3, WpR, b_s, B1, N_NODES);

    // ---- global mean pool (two-stage, no atomics) ----
    pool_partial<<<N_GRAPHS * SLICES, 128, 0, stream>>>(B1, batch, part);
    pool_reduce<<<N_GRAPHS, 128, 0, stream>>>(part, batch, out);
}

// Round 19
// 260.157 us; speedup vs baseline: 1.6232x; 1.0364x over previous
//
#include <hip/hip_runtime.h>

#define N_NODES 50000
#define N_EDGES 600000
#define HIDDEN 128
#define N_GRAPHS 64
#define SLICES 16
#define SCAN_B ((N_NODES + 255) / 256)   // 196

typedef __attribute__((ext_vector_type(8))) short bf16x8;
typedef __attribute__((ext_vector_type(4))) float f32x4;

__device__ inline ushort f2bf(float v) {
    union { float f; unsigned u; } x; x.f = v;
    unsigned r = (x.u + 0x7FFF + ((x.u >> 16) & 1)) >> 16;  // RNE
    return (ushort)r;
}
__device__ inline float bf2f(ushort h) {
    union { unsigned u; float f; } x; x.u = ((unsigned)h) << 16;
    return x.f;
}

// Inter-kernel node features: bf16 ROW-MAJOR (256B rows). Pool input: fp32
// feature-chunked: elem(n,f) at ((f>>4)*N + n)*16 + (f&15).

// ---------------- degree ----------------

__global__ void deg_kernel(const int* __restrict__ dst, int* __restrict__ deg) {
    int t = blockIdx.x * 256 + threadIdx.x;
    if (t < N_EDGES) atomicAdd(&deg[dst[t]], 1);
}

// ---------------- 3-pass parallel scan: deg -> rowptr (+ fused dinv) ----------------

__global__ void scan_partial(const int* __restrict__ deg, int* __restrict__ bsum) {
    const int b = blockIdx.x, t = threadIdx.x;
    const int i = b * 256 + t;
    int v = (i < N_NODES) ? deg[i] : 0;
    __shared__ int wsum[4];
#pragma unroll
    for (int o = 32; o > 0; o >>= 1) v += __shfl_down(v, o, 64);
    if ((t & 63) == 0) wsum[t >> 6] = v;
    __syncthreads();
    if (t == 0) bsum[b] = wsum[0] + wsum[1] + wsum[2] + wsum[3];
}

__global__ void scan_bsum(const int* __restrict__ bsum, int* __restrict__ boff,
                          int* __restrict__ rowptr) {
    __shared__ int s[256];
    const int t = threadIdx.x;
    const int v = (t < SCAN_B) ? bsum[t] : 0;
    s[t] = v;
    __syncthreads();
    for (int o = 1; o < 256; o <<= 1) {
        int u = (t >= o) ? s[t - o] : 0;
        __syncthreads();
        s[t] += u;
        __syncthreads();
    }
    if (t < SCAN_B) boff[t] = s[t] - v;      // exclusive
    if (t == 255) rowptr[N_NODES] = s[255];  // total == N_EDGES
}

__global__ void scan_final(const int* __restrict__ deg, const int* __restrict__ boff,
                           int* __restrict__ rowptr, float* __restrict__ dinv) {
    const int b = blockIdx.x, t = threadIdx.x;
    const int i = b * 256 + t;
    __shared__ int s[256];
    const int v = (i < N_NODES) ? deg[i] : 0;
    s[t] = v;
    __syncthreads();
    for (int o = 1; o < 256; o <<= 1) {
        int u = (t >= o) ? s[t - o] : 0;
        __syncthreads();
        s[t] += u;
        __syncthreads();
    }
    if (i < N_NODES) {
        rowptr[i] = boff[b] + s[t] - v;
        dinv[i] = rsqrtf((float)v + 1.0f);
    }
}

// ---------------- CSR fill: interleaved {src, norm} ----------------

__global__ void fill_kernel(const int* __restrict__ src, const int* __restrict__ dst,
                            const int* __restrict__ rowptr, int* __restrict__ fillcnt,
                            const float* __restrict__ dinv, int2* __restrict__ csr) {
    int e = blockIdx.x * 256 + threadIdx.x;
    if (e >= N_EDGES) return;
    const int d = dst[e];
    const int s = src[e];
    const int pos = rowptr[d] + atomicAdd(&fillcnt[d], 1);
    csr[pos] = make_int2(s, __float_as_int(dinv[s] * dinv[d]));
}

// ---------------- W pack: fp32 [128k][128n] -> bf16 hi/lo in MFMA fragment order --

__global__ void pack_w(const float* __restrict__ Wa, const float* __restrict__ Wb,
                       const float* __restrict__ Wc, const float* __restrict__ Wd,
                       ushort* __restrict__ out) {
    const int m = blockIdx.x >> 3;
    const int gid = (blockIdx.x & 7) * 256 + threadIdx.x;  // 0..2047
    const float* W = (m == 0) ? Wa : (m == 1) ? Wb : (m == 2) ? Wc : Wd;
    const int s = gid >> 9;
    const int c = (gid >> 6) & 7;
    const int lane = gid & 63;
    const int kbase = s * 32 + 8 * (lane >> 4);
    const int n = c * 16 + (lane & 15);
    ushort* hi = out + (long)m * 32768;
    ushort* lo = hi + 16384;
#pragma unroll
    for (int j = 0; j < 8; j++) {
        const float v = W[(kbase + j) * HIDDEN + n];
        const ushort h = f2bf(v);
        hi[gid * 8 + j] = h;
        lo[gid * 8 + j] = f2bf(v - bf2f(h));
    }
}

// ---------------- GEMM1: fp32 row-major A (= x) @ W -> bf16 rows; bf16x3 --------

__global__ void gemm_f32in(const float* __restrict__ A, const ushort* __restrict__ Wp,
                           ushort* __restrict__ Cb, int nrows) {
    __shared__ alignas(16) ushort Ah[64 * 128];
    __shared__ alignas(16) ushort Al[64 * 128];
    const int r0 = blockIdx.x * 64;
    const int tid = threadIdx.x;

#pragma unroll
    for (int i = 0; i < 8; i++) {
        const int idx = tid + i * 256;          // 0..2047 float4 slots
        const int node = idx >> 5;              // 0..63
        const int f0 = 4 * (idx & 31);
        float4 v = make_float4(0.f, 0.f, 0.f, 0.f);
        if (r0 + node < nrows)
            v = reinterpret_cast<const float4*>(A + (long)r0 * HIDDEN)[idx];
        const ushort h0 = f2bf(v.x), h1 = f2bf(v.y), h2 = f2bf(v.z), h3 = f2bf(v.w);
        ushort4 h4; h4.x = h0; h4.y = h1; h4.z = h2; h4.w = h3;
        ushort4 l4;
        l4.x = f2bf(v.x - bf2f(h0)); l4.y = f2bf(v.y - bf2f(h1));
        l4.z = f2bf(v.z - bf2f(h2)); l4.w = f2bf(v.w - bf2f(h3));
        const int kb = (2 * f0) ^ ((node & 7) << 4);
        *reinterpret_cast<ushort4*>(&Ah[(node * 256 + kb) >> 1]) = h4;
        *reinterpret_cast<ushort4*>(&Al[(node * 256 + kb) >> 1]) = l4;
    }
    __syncthreads();

    const int wave = tid >> 6;
    const int lane = tid & 63;
    const int arow = 16 * wave + (lane & 15);

    f32x4 acc[8];
#pragma unroll
    for (int c = 0; c < 8; c++) acc[c] = (f32x4){0.f, 0.f, 0.f, 0.f};

#pragma unroll
    for (int s = 0; s < 4; s++) {
        const int koff = (s * 64 + ((lane >> 4) << 4)) ^ ((arow & 7) << 4);
        const bf16x8 ahi = *reinterpret_cast<const bf16x8*>(&Ah[(arow * 256 + koff) >> 1]);
        const bf16x8 alo = *reinterpret_cast<const bf16x8*>(&Al[(arow * 256 + koff) >> 1]);
#pragma unroll
        for (int c = 0; c < 8; c++) {
            const bf16x8 bhi = *reinterpret_cast<const bf16x8*>(&Wp[((s * 8 + c) * 64 + lane) * 8]);
            const bf16x8 blo = *reinterpret_cast<const bf16x8*>(&Wp[16384 + ((s * 8 + c) * 64 + lane) * 8]);
            acc[c] = __builtin_amdgcn_mfma_f32_16x16x32_bf16(ahi, bhi, acc[c], 0, 0, 0);
            acc[c] = __builtin_amdgcn_mfma_f32_16x16x32_bf16(alo, bhi, acc[c], 0, 0, 0);
            acc[c] = __builtin_amdgcn_mfma_f32_16x16x32_bf16(ahi, blo, acc[c], 0, 0, 0);
        }
    }

    const int node0 = r0 + 16 * wave + ((lane >> 4) << 2);
    const int fc = lane & 15;
#pragma unroll
    for (int c = 0; c < 8; c++) {
#pragma unroll
        for (int reg = 0; reg < 4; reg++) {
            const int node = node0 + reg;
            if (node < nrows)
                Cb[(long)node * HIDDEN + c * 16 + fc] = f2bf(acc[c][reg]);
        }
    }
}

// ---------------- bf16-input staging helper (16 KB LDS, XOR swizzle) ------------

__device__ inline void stage_bf16(const ushort* __restrict__ Ab, ushort* __restrict__ Ah,
                                  int r0, int tid, int nrows) {
#pragma unroll
    for (int i = 0; i < 4; i++) {
        const int idx = tid + i * 256;          // 0..1023 bf16x8 slots
        const int node = idx >> 4;              // 0..63
        const int g = idx & 15;                 // 16B group
        bf16x8 v = (bf16x8){0, 0, 0, 0, 0, 0, 0, 0};
        if (r0 + node < nrows)
            v = *reinterpret_cast<const bf16x8*>(Ab + (long)(r0 + node) * HIDDEN + g * 8);
        const int kb = (g * 16) ^ ((node & 7) << 4);
        *reinterpret_cast<bf16x8*>(&Ah[(node * 256 + kb) >> 1]) = v;
    }
}

// ---------------- GEMM2: bf16 rows A @ W -> bf16 rows; 2-term MFMA --------------

__global__ void gemm_bf16in(const ushort* __restrict__ Ab, const ushort* __restrict__ Wp,
                            ushort* __restrict__ Cb, int nrows) {
    __shared__ alignas(16) ushort Ah[64 * 128];
    const int r0 = blockIdx.x * 64;
    const int tid = threadIdx.x;

    stage_bf16(Ab, Ah, r0, tid, nrows);
    __syncthreads();

    const int wave = tid >> 6;
    const int lane = tid & 63;
    const int arow = 16 * wave + (lane & 15);

    f32x4 acc[8];
#pragma unroll
    for (int c = 0; c < 8; c++) acc[c] = (f32x4){0.f, 0.f, 0.f, 0.f};

#pragma unroll
    for (int s = 0; s < 4; s++) {
        const int koff = (s * 64 + ((lane >> 4) << 4)) ^ ((arow & 7) << 4);
        const bf16x8 ahi = *reinterpret_cast<const bf16x8*>(&Ah[(arow * 256 + koff) >> 1]);
#pragma unroll
        for (int c = 0; c < 8; c++) {
            const bf16x8 bhi = *reinterpret_cast<const bf16x8*>(&Wp[((s * 8 + c) * 64 + lane) * 8]);
            const bf16x8 blo = *reinterpret_cast<const bf16x8*>(&Wp[16384 + ((s * 8 + c) * 64 + lane) * 8]);
            acc[c] = __builtin_amdgcn_mfma_f32_16x16x32_bf16(ahi, bhi, acc[c], 0, 0, 0);
            acc[c] = __builtin_amdgcn_mfma_f32_16x16x32_bf16(ahi, blo, acc[c], 0, 0, 0);
        }
    }

    const int node0 = r0 + 16 * wave + ((lane >> 4) << 2);
    const int fc = lane & 15;
#pragma unroll
    for (int c = 0; c < 8; c++) {
#pragma unroll
        for (int reg = 0; reg < 4; reg++) {
            const int node = node0 + reg;
            if (node < nrows)
                Cb[(long)node * HIDDEN + c * 16 + fc] = f2bf(acc[c][reg]);
        }
    }
}

// ---------------- SAGE GEMM: bf16 A1@Wl + bf16 A2@Wr + b -> fp32 chunked --------

__global__ void gemm_sage_bf16in(const ushort* __restrict__ A1, const ushort* __restrict__ Wp1,
                                 const ushort* __restrict__ A2, const ushort* __restrict__ Wp2,
                                 const float* __restrict__ bias, float* __restrict__ C,
                                 int nrows) {
    __shared__ alignas(16) ushort Ah[64 * 128];
    const int r0 = blockIdx.x * 64;
    const int tid = threadIdx.x;
    const int wave = tid >> 6;
    const int lane = tid & 63;
    const int arow = 16 * wave + (lane & 15);

    f32x4 acc[8];
#pragma unroll
    for (int c = 0; c < 8; c++) acc[c] = (f32x4){0.f, 0.f, 0.f, 0.f};

    for (int p = 0; p < 2; p++) {
        const ushort* Ab = (p == 0) ? A1 : A2;
        const ushort* Wp = (p == 0) ? Wp1 : Wp2;
        if (p) __syncthreads();
        stage_bf16(Ab, Ah, r0, tid, nrows);
        __syncthreads();

#pragma unroll
        for (int s = 0; s < 4; s++) {
            const int koff = (s * 64 + ((lane >> 4) << 4)) ^ ((arow & 7) << 4);
            const bf16x8 ahi = *reinterpret_cast<const bf16x8*>(&Ah[(arow * 256 + koff) >> 1]);
#pragma unroll
            for (int c = 0; c < 8; c++) {
                const bf16x8 bhi = *reinterpret_cast<const bf16x8*>(&Wp[((s * 8 + c) * 64 + lane) * 8]);
                const bf16x8 blo = *reinterpret_cast<const bf16x8*>(&Wp[16384 + ((s * 8 + c) * 64 + lane) * 8]);
                acc[c] = __builtin_amdgcn_mfma_f32_16x16x32_bf16(ahi, bhi, acc[c], 0, 0, 0);
                acc[c] = __builtin_amdgcn_mfma_f32_16x16x32_bf16(ahi, blo, acc[c], 0, 0, 0);
            }
        }
    }

    const int node0 = r0 + 16 * wave + ((lane >> 4) << 2);
    const int fc = lane & 15;
#pragma unroll
    for (int c = 0; c < 8; c++) {
        const float bb = bias[c * 16 + fc];
#pragma unroll
        for (int reg = 0; reg < 4; reg++) {
            const int node = node0 + reg;
            if (node < nrows)
                C[((long)c * N_NODES + node) * 16 + fc] = acc[c][reg] + bb;
        }
    }
}

// ---------------- GCN gather: bf16 rows in -> bf16 rows out ---------------------
// wave = 2 nodes x 32 lanes; lane l handles features l*4..l*4+3.

__global__ void gather_gcn(const ushort* __restrict__ hb, const int* __restrict__ rowptr,
                           const int2* __restrict__ csr, const float* __restrict__ dinv,
                           const float* __restrict__ bias, ushort* __restrict__ outB) {
    const int tid = threadIdx.x;
    const int d = blockIdx.x * 8 + (tid >> 5);
    if (d >= N_NODES) return;
    const int l = tid & 31;
    const float di = dinv[d];
    const int beg = rowptr[d];
    const int end = rowptr[d + 1];
    float a0 = 0.f, a1 = 0.f, a2 = 0.f, a3 = 0.f;
    int j = beg;
    for (; j + 2 <= end; j += 2) {
        const int2 e0 = csr[j];
        const int2 e1 = csr[j + 1];
        const float n0 = __int_as_float(e0.y);
        const float n1 = __int_as_float(e1.y);
        const ushort4 u0 = *reinterpret_cast<const ushort4*>(hb + (long)e0.x * HIDDEN + l * 4);
        const ushort4 u1 = *reinterpret_cast<const ushort4*>(hb + (long)e1.x * HIDDEN + l * 4);
        a0 += bf2f(u0.x) * n0 + bf2f(u1.x) * n1;
        a1 += bf2f(u0.y) * n0 + bf2f(u1.y) * n1;
        a2 += bf2f(u0.z) * n0 + bf2f(u1.z) * n1;
        a3 += bf2f(u0.w) * n0 + bf2f(u1.w) * n1;
    }
    if (j < end) {
        const int2 e0 = csr[j];
        const float n0 = __int_as_float(e0.y);
        const ushort4 u0 = *reinterpret_cast<const ushort4*>(hb + (long)e0.x * HIDDEN + l * 4);
        a0 += bf2f(u0.x) * n0;
        a1 += bf2f(u0.y) * n0;
        a2 += bf2f(u0.z) * n0;
        a3 += bf2f(u0.w) * n0;
    }
    const ushort4 us = *reinterpret_cast<const ushort4*>(hb + (long)d * HIDDEN + l * 4);
    const float4 b = *reinterpret_cast<const float4*>(bias + l * 4);
    const float invdeg = di * di;
    ushort4 o;
    o.x = f2bf(fmaxf(a0 + bf2f(us.x) * invdeg + b.x, 0.f));
    o.y = f2bf(fmaxf(a1 + bf2f(us.y) * invdeg + b.y, 0.f));
    o.z = f2bf(fmaxf(a2 + bf2f(us.z) * invdeg + b.z, 0.f));
    o.w = f2bf(fmaxf(a3 + bf2f(us.w) * invdeg + b.w, 0.f));
    *reinterpret_cast<ushort4*>(outB + (long)d * HIDDEN + l * 4) = o;
}

// ---------------- SAGE mean gather: bf16 rows in -> bf16 rows out ---------------

__global__ void gather_sage(const ushort* __restrict__ hb, const int* __restrict__ rowptr,
                            const int2* __restrict__ csr, ushort* __restrict__ mean) {
    const int tid = threadIdx.x;
    const int d = blockIdx.x * 8 + (tid >> 5);
    if (d >= N_NODES) return;
    const int l = tid & 31;
    const int beg = rowptr[d];
    const int end = rowptr[d + 1];
    float a0 = 0.f, a1 = 0.f, a2 = 0.f, a3 = 0.f;
    int j = beg;
    for (; j + 2 <= end; j += 2) {
        const int2 e0 = csr[j];
        const int2 e1 = csr[j + 1];
        const ushort4 u0 = *reinterpret_cast<const ushort4*>(hb + (long)e0.x * HIDDEN + l * 4);
        const ushort4 u1 = *reinterpret_cast<const ushort4*>(hb + (long)e1.x * HIDDEN + l * 4);
        a0 += bf2f(u0.x) + bf2f(u1.x);
        a1 += bf2f(u0.y) + bf2f(u1.y);
        a2 += bf2f(u0.z) + bf2f(u1.z);
        a3 += bf2f(u0.w) + bf2f(u1.w);
    }
    if (j < end) {
        const int2 e0 = csr[j];
        const ushort4 u0 = *reinterpret_cast<const ushort4*>(hb + (long)e0.x * HIDDEN + l * 4);
        a0 += bf2f(u0.x);
        a1 += bf2f(u0.y);
        a2 += bf2f(u0.z);
        a3 += bf2f(u0.w);
    }
    const float inv = 1.0f / fmaxf((float)(end - beg), 1.0f);
    ushort4 o;
    o.x = f2bf(a0 * inv); o.y = f2bf(a1 * inv);
    o.z = f2bf(a2 * inv); o.w = f2bf(a3 * inv);
    *reinterpret_cast<ushort4*>(mean + (long)d * HIDDEN + l * 4) = o;
}

// ---------------- pooling (two-stage; batch sorted; fp32 chunked input) ---------

__device__ int lower_bound_batch(const int* __restrict__ batch, int key) {
    int lo = 0, hi = N_NODES;
    while (lo < hi) {
        int mid = (lo + hi) >> 1;
        if (batch[mid] < key) lo = mid + 1;
        else hi = mid;
    }
    return lo;
}

__global__ void pool_partial(const float* __restrict__ node, const int* __restrict__ batch,
                             float* __restrict__ part) {
    const int b = blockIdx.x;          // g * SLICES + k
    const int g = b / SLICES;
    const int k = b % SLICES;
    const int t = threadIdx.x;         // feature t
    const long cbase = (long)(t >> 4) * N_NODES;
    const int foff = t & 15;
    const int lo = lower_bound_batch(batch, g);
    const int hi = lower_bound_batch(batch, g + 1);
    const int len = hi - lo;
    const int per = (len + SLICES - 1) / SLICES;
    const int s = lo + k * per;
    const int e = min(s + per, hi);
    float acc = 0.f;
    for (int i = s; i < e; i++) acc += node[(cbase + i) * 16 + foff];
    part[(long)b * HIDDEN + t] = acc;
}

__global__ void pool_reduce(const float* __restrict__ part, const int* __restrict__ batch,
                            float* __restrict__ out) {
    const int g = blockIdx.x;
    const int t = threadIdx.x;
    float acc = 0.f;
#pragma unroll
    for (int k = 0; k < SLICES; k++) acc += part[(long)(g * SLICES + k) * HIDDEN + t];
    const int lo = lower_bound_batch(batch, g);
    const int hi = lower_bound_batch(batch, g + 1);
    out[g * HIDDEN + t] = acc / fmaxf((float)(hi - lo), 1.0f);
}

// ---------------- launch ----------------

extern "C" void kernel_launch(void* const* d_in, const int* in_sizes, int n_in,
                              void* d_out, int out_size, void* d_ws, size_t ws_size,
                              hipStream_t stream) {
    const float* x    = (const float*)d_in[0];
    const int*   ei   = (const int*)d_in[1];   // [2][E]
    const int*   batch= (const int*)d_in[2];
    const float* W1   = (const float*)d_in[3];
    const float* b1   = (const float*)d_in[4];
    const float* W2   = (const float*)d_in[5];
    const float* b2   = (const float*)d_in[6];
    const float* W_l  = (const float*)d_in[7];
    const float* W_r  = (const float*)d_in[8];
    const float* b_s  = (const float*)d_in[9];
    float* out = (float*)d_out;

    const int* src = ei;
    const int* dst = ei + N_EDGES;

    // workspace layout (all disjoint)
    char* ws = (char*)d_ws;
    const size_t NB = (size_t)N_NODES * HIDDEN * sizeof(float);    // 25.6 MB
    const size_t HB = (size_t)N_NODES * HIDDEN * sizeof(ushort);   // 12.8 MB
    float*  SOUT = (float*)(ws);                 // fp32 chunked (sage out, pool in)
    ushort* HP   = (ushort*)(ws + NB);           // bf16 rows: gemm1/2 out
    ushort* G1   = (ushort*)(ws + NB + HB);      // bf16 rows: gather1 out / mean
    ushort* G2   = (ushort*)(ws + 2 * NB);       // bf16 rows: gather2 out
    ushort* MEAN = (ushort*)(ws + 2 * NB + HB);  // bf16 rows: sage mean
    size_t off = 3 * NB;
    int*   deg      = (int*)(ws + off);   off += (size_t)N_NODES * 4;
    float* dinv     = (float*)(ws + off); off += (size_t)N_NODES * 4;
    int*   rowptr   = (int*)(ws + off);   off += (size_t)(N_NODES + 1) * 4;
    int*   fillcnt  = (int*)(ws + off);   off += (size_t)N_NODES * 4;
    int2*  csr      = (int2*)(ws + off);  off += (size_t)N_EDGES * 8;
    float* part     = (float*)(ws + off); off += (size_t)N_GRAPHS * SLICES * HIDDEN * 4;
    int*   bsum     = (int*)(ws + off);   off += (size_t)SCAN_B * 4;
    int*   boff     = (int*)(ws + off);   off += (size_t)SCAN_B * 4;
    ushort* wpack   = (ushort*)(ws + off); off += (size_t)4 * 32768 * 2;

    const ushort* Wp1 = wpack;                // W1
    const ushort* Wp2 = wpack + 32768;        // W2
    const ushort* WpL = wpack + 2 * 32768;    // W_l
    const ushort* WpR = wpack + 3 * 32768;    // W_r

    const int EB = (N_EDGES + 255) / 256;
    const int GB = (N_NODES + 63) / 64;   // 64-row MFMA tiles (782)
    const int GTB = (N_NODES + 7) / 8;    // gather blocks (8 nodes/block)

    // ---- pack weights (bf16 hi/lo, fragment order) ----
    pack_w<<<32, 256, 0, stream>>>(W1, W2, W_l, W_r, wpack);

    // ---- build CSR (once per call) ----
    hipMemsetAsync(deg, 0, (size_t)N_NODES * 4, stream);
    hipMemsetAsync(fillcnt, 0, (size_t)N_NODES * 4, stream);
    deg_kernel<<<EB, 256, 0, stream>>>(dst, deg);
    scan_partial<<<SCAN_B, 256, 0, stream>>>(deg, bsum);
    scan_bsum<<<1, 256, 0, stream>>>(bsum, boff, rowptr);
    scan_final<<<SCAN_B, 256, 0, stream>>>(deg, boff, rowptr, dinv);
    fill_kernel<<<EB, 256, 0, stream>>>(src, dst, rowptr, fillcnt, dinv, csr);

    // ---- GCN layer 1 ----
    gemm_f32in<<<GB, 256, 0, stream>>>(x, Wp1, HP, N_NODES);
    gather_gcn<<<GTB, 256, 0, stream>>>(HP, rowptr, csr, dinv, b1, G1);

    // ---- GCN layer 2 ----
    gemm_bf16in<<<GB, 256, 0, stream>>>(G1, Wp2, HP, N_NODES);
    gather_gcn<<<GTB, 256, 0, stream>>>(HP, rowptr, csr, dinv, b2, G2);

    // ---- SAGE ----
    gather_sage<<<GTB, 256, 0, stream>>>(G2, rowptr, csr, MEAN);
    gemm_sage_bf16in<<<GB, 256, 0, stream>>>(MEAN, WpL, G2, WpR, b_s, SOUT, N_NODES);

    // ---- global mean pool (two-stage, no atomics) ----
    pool_partial<<<N_GRAPHS * SLICES, 128, 0, stream>>>(SOUT, batch, part);
    pool_reduce<<<N_GRAPHS, 128, 0, stream>>>(part, batch, out);
}

// Round 20
// 244.919 us; speedup vs baseline: 1.7242x; 1.0622x over previous
//
#include <hip/hip_runtime.h>

#define N_NODES 50000
#define N_EDGES 600000
#define HIDDEN 128
#define N_GRAPHS 64
#define SLICES 16
#define SCAN_B ((N_NODES + 255) / 256)   // 196

typedef __attribute__((ext_vector_type(8))) short bf16x8;
typedef __attribute__((ext_vector_type(4))) float f32x4;

__device__ inline ushort f2bf(float v) {
    union { float f; unsigned u; } x; x.f = v;
    unsigned r = (x.u + 0x7FFF + ((x.u >> 16) & 1)) >> 16;  // RNE
    return (ushort)r;
}
__device__ inline float bf2f(ushort h) {
    union { unsigned u; float f; } x; x.u = ((unsigned)h) << 16;
    return x.f;
}

// Inter-kernel node features: bf16 ROW-MAJOR (256B rows). Pool input: fp32
// feature-chunked: elem(n,f) at ((f>>4)*N + n)*16 + (f&15).

// ---------------- degree ----------------

__global__ void deg_kernel(const int* __restrict__ dst, int* __restrict__ deg) {
    int t = blockIdx.x * 256 + threadIdx.x;
    if (t < N_EDGES) atomicAdd(&deg[dst[t]], 1);
}

// ---------------- 3-pass parallel scan: deg -> rowptr (+ fused dinv) ----------------

__global__ void scan_partial(const int* __restrict__ deg, int* __restrict__ bsum) {
    const int b = blockIdx.x, t = threadIdx.x;
    const int i = b * 256 + t;
    int v = (i < N_NODES) ? deg[i] : 0;
    __shared__ int wsum[4];
#pragma unroll
    for (int o = 32; o > 0; o >>= 1) v += __shfl_down(v, o, 64);
    if ((t & 63) == 0) wsum[t >> 6] = v;
    __syncthreads();
    if (t == 0) bsum[b] = wsum[0] + wsum[1] + wsum[2] + wsum[3];
}

__global__ void scan_bsum(const int* __restrict__ bsum, int* __restrict__ boff,
                          int* __restrict__ rowptr) {
    __shared__ int s[256];
    const int t = threadIdx.x;
    const int v = (t < SCAN_B) ? bsum[t] : 0;
    s[t] = v;
    __syncthreads();
    for (int o = 1; o < 256; o <<= 1) {
        int u = (t >= o) ? s[t - o] : 0;
        __syncthreads();
        s[t] += u;
        __syncthreads();
    }
    if (t < SCAN_B) boff[t] = s[t] - v;      // exclusive
    if (t == 255) rowptr[N_NODES] = s[255];  // total == N_EDGES
}

__global__ void scan_final(const int* __restrict__ deg, const int* __restrict__ boff,
                           int* __restrict__ rowptr, float* __restrict__ dinv) {
    const int b = blockIdx.x, t = threadIdx.x;
    const int i = b * 256 + t;
    __shared__ int s[256];
    const int v = (i < N_NODES) ? deg[i] : 0;
    s[t] = v;
    __syncthreads();
    for (int o = 1; o < 256; o <<= 1) {
        int u = (t >= o) ? s[t - o] : 0;
        __syncthreads();
        s[t] += u;
        __syncthreads();
    }
    if (i < N_NODES) {
        rowptr[i] = boff[b] + s[t] - v;
        dinv[i] = rsqrtf((float)v + 1.0f);
    }
}

// ---------------- CSR fill: interleaved {src, norm} ----------------

__global__ void fill_kernel(const int* __restrict__ src, const int* __restrict__ dst,
                            const int* __restrict__ rowptr, int* __restrict__ fillcnt,
                            const float* __restrict__ dinv, int2* __restrict__ csr) {
    int e = blockIdx.x * 256 + threadIdx.x;
    if (e >= N_EDGES) return;
    const int d = dst[e];
    const int s = src[e];
    const int pos = rowptr[d] + atomicAdd(&fillcnt[d], 1);
    csr[pos] = make_int2(s, __float_as_int(dinv[s] * dinv[d]));
}

// ---------------- W pack: fp32 [128k][128n] -> bf16 hi/lo in MFMA fragment order --

__global__ void pack_w(const float* __restrict__ Wa, const float* __restrict__ Wb,
                       const float* __restrict__ Wc, const float* __restrict__ Wd,
                       ushort* __restrict__ out) {
    const int m = blockIdx.x >> 3;
    const int gid = (blockIdx.x & 7) * 256 + threadIdx.x;  // 0..2047
    const float* W = (m == 0) ? Wa : (m == 1) ? Wb : (m == 2) ? Wc : Wd;
    const int s = gid >> 9;
    const int c = (gid >> 6) & 7;
    const int lane = gid & 63;
    const int kbase = s * 32 + 8 * (lane >> 4);
    const int n = c * 16 + (lane & 15);
    ushort* hi = out + (long)m * 32768;
    ushort* lo = hi + 16384;
#pragma unroll
    for (int j = 0; j < 8; j++) {
        const float v = W[(kbase + j) * HIDDEN + n];
        const ushort h = f2bf(v);
        hi[gid * 8 + j] = h;
        lo[gid * 8 + j] = f2bf(v - bf2f(h));
    }
}

// ---------------- GEMM1: fp32 row-major A (= x) @ W -> bf16 rows; bf16x3 --------

__global__ void gemm_f32in(const float* __restrict__ A, const ushort* __restrict__ Wp,
                           ushort* __restrict__ Cb, int nrows) {
    __shared__ alignas(16) ushort Ah[64 * 128];
    __shared__ alignas(16) ushort Al[64 * 128];
    const int r0 = blockIdx.x * 64;
    const int tid = threadIdx.x;

#pragma unroll
    for (int i = 0; i < 8; i++) {
        const int idx = tid + i * 256;          // 0..2047 float4 slots
        const int node = idx >> 5;              // 0..63
        const int f0 = 4 * (idx & 31);
        float4 v = make_float4(0.f, 0.f, 0.f, 0.f);
        if (r0 + node < nrows)
            v = reinterpret_cast<const float4*>(A + (long)r0 * HIDDEN)[idx];
        const ushort h0 = f2bf(v.x), h1 = f2bf(v.y), h2 = f2bf(v.z), h3 = f2bf(v.w);
        ushort4 h4; h4.x = h0; h4.y = h1; h4.z = h2; h4.w = h3;
        ushort4 l4;
        l4.x = f2bf(v.x - bf2f(h0)); l4.y = f2bf(v.y - bf2f(h1));
        l4.z = f2bf(v.z - bf2f(h2)); l4.w = f2bf(v.w - bf2f(h3));
        const int kb = (2 * f0) ^ ((node & 7) << 4);
        *reinterpret_cast<ushort4*>(&Ah[(node * 256 + kb) >> 1]) = h4;
        *reinterpret_cast<ushort4*>(&Al[(node * 256 + kb) >> 1]) = l4;
    }
    __syncthreads();

    const int wave = tid >> 6;
    const int lane = tid & 63;
    const int arow = 16 * wave + (lane & 15);

    f32x4 acc[8];
#pragma unroll
    for (int c = 0; c < 8; c++) acc[c] = (f32x4){0.f, 0.f, 0.f, 0.f};

#pragma unroll
    for (int s = 0; s < 4; s++) {
        const int koff = (s * 64 + ((lane >> 4) << 4)) ^ ((arow & 7) << 4);
        const bf16x8 ahi = *reinterpret_cast<const bf16x8*>(&Ah[(arow * 256 + koff) >> 1]);
        const bf16x8 alo = *reinterpret_cast<const bf16x8*>(&Al[(arow * 256 + koff) >> 1]);
#pragma unroll
        for (int c = 0; c < 8; c++) {
            const bf16x8 bhi = *reinterpret_cast<const bf16x8*>(&Wp[((s * 8 + c) * 64 + lane) * 8]);
            const bf16x8 blo = *reinterpret_cast<const bf16x8*>(&Wp[16384 + ((s * 8 + c) * 64 + lane) * 8]);
            acc[c] = __builtin_amdgcn_mfma_f32_16x16x32_bf16(ahi, bhi, acc[c], 0, 0, 0);
            acc[c] = __builtin_amdgcn_mfma_f32_16x16x32_bf16(alo, bhi, acc[c], 0, 0, 0);
            acc[c] = __builtin_amdgcn_mfma_f32_16x16x32_bf16(ahi, blo, acc[c], 0, 0, 0);
        }
    }

    const int node0 = r0 + 16 * wave + ((lane >> 4) << 2);
    const int fc = lane & 15;
#pragma unroll
    for (int c = 0; c < 8; c++) {
#pragma unroll
        for (int reg = 0; reg < 4; reg++) {
            const int node = node0 + reg;
            if (node < nrows)
                Cb[(long)node * HIDDEN + c * 16 + fc] = f2bf(acc[c][reg]);
        }
    }
}

// ---------------- bf16-input staging helper (16 KB LDS, XOR swizzle) ------------

__device__ inline void stage_bf16(const ushort* __restrict__ Ab, ushort* __restrict__ Ah,
                                  int r0, int tid, int nrows) {
#pragma unroll
    for (int i = 0; i < 4; i++) {
        const int idx = tid + i * 256;          // 0..1023 bf16x8 slots
        const int node = idx >> 4;              // 0..63
        const int g = idx & 15;                 // 16B group
        bf16x8 v = (bf16x8){0, 0, 0, 0, 0, 0, 0, 0};
        if (r0 + node < nrows)
            v = *reinterpret_cast<const bf16x8*>(Ab + (long)(r0 + node) * HIDDEN + g * 8);
        const int kb = (g * 16) ^ ((node & 7) << 4);
        *reinterpret_cast<bf16x8*>(&Ah[(node * 256 + kb) >> 1]) = v;
    }
}

// ---------------- GEMM2: bf16 rows A @ W -> bf16 rows; 2-term MFMA --------------

__global__ void gemm_bf16in(const ushort* __restrict__ Ab, const ushort* __restrict__ Wp,
                            ushort* __restrict__ Cb, int nrows) {
    __shared__ alignas(16) ushort Ah[64 * 128];
    const int r0 = blockIdx.x * 64;
    const int tid = threadIdx.x;

    stage_bf16(Ab, Ah, r0, tid, nrows);
    __syncthreads();

    const int wave = tid >> 6;
    const int lane = tid & 63;
    const int arow = 16 * wave + (lane & 15);

    f32x4 acc[8];
#pragma unroll
    for (int c = 0; c < 8; c++) acc[c] = (f32x4){0.f, 0.f, 0.f, 0.f};

#pragma unroll
    for (int s = 0; s < 4; s++) {
        const int koff = (s * 64 + ((lane >> 4) << 4)) ^ ((arow & 7) << 4);
        const bf16x8 ahi = *reinterpret_cast<const bf16x8*>(&Ah[(arow * 256 + koff) >> 1]);
#pragma unroll
        for (int c = 0; c < 8; c++) {
            const bf16x8 bhi = *reinterpret_cast<const bf16x8*>(&Wp[((s * 8 + c) * 64 + lane) * 8]);
            const bf16x8 blo = *reinterpret_cast<const bf16x8*>(&Wp[16384 + ((s * 8 + c) * 64 + lane) * 8]);
            acc[c] = __builtin_amdgcn_mfma_f32_16x16x32_bf16(ahi, bhi, acc[c], 0, 0, 0);
            acc[c] = __builtin_amdgcn_mfma_f32_16x16x32_bf16(ahi, blo, acc[c], 0, 0, 0);
        }
    }

    const int node0 = r0 + 16 * wave + ((lane >> 4) << 2);
    const int fc = lane & 15;
#pragma unroll
    for (int c = 0; c < 8; c++) {
#pragma unroll
        for (int reg = 0; reg < 4; reg++) {
            const int node = node0 + reg;
            if (node < nrows)
                Cb[(long)node * HIDDEN + c * 16 + fc] = f2bf(acc[c][reg]);
        }
    }
}

// ---------------- SAGE GEMM: bf16 A1@Wl + bf16 A2@Wr + b -> fp32 chunked --------

__global__ void gemm_sage_bf16in(const ushort* __restrict__ A1, const ushort* __restrict__ Wp1,
                                 const ushort* __restrict__ A2, const ushort* __restrict__ Wp2,
                                 const float* __restrict__ bias, float* __restrict__ C,
                                 int nrows) {
    __shared__ alignas(16) ushort Ah[64 * 128];
    const int r0 = blockIdx.x * 64;
    const int tid = threadIdx.x;
    const int wave = tid >> 6;
    const int lane = tid & 63;
    const int arow = 16 * wave + (lane & 15);

    f32x4 acc[8];
#pragma unroll
    for (int c = 0; c < 8; c++) acc[c] = (f32x4){0.f, 0.f, 0.f, 0.f};

    for (int p = 0; p < 2; p++) {
        const ushort* Ab = (p == 0) ? A1 : A2;
        const ushort* Wp = (p == 0) ? Wp1 : Wp2;
        if (p) __syncthreads();
        stage_bf16(Ab, Ah, r0, tid, nrows);
        __syncthreads();

#pragma unroll
        for (int s = 0; s < 4; s++) {
            const int koff = (s * 64 + ((lane >> 4) << 4)) ^ ((arow & 7) << 4);
            const bf16x8 ahi = *reinterpret_cast<const bf16x8*>(&Ah[(arow * 256 + koff) >> 1]);
#pragma unroll
            for (int c = 0; c < 8; c++) {
                const bf16x8 bhi = *reinterpret_cast<const bf16x8*>(&Wp[((s * 8 + c) * 64 + lane) * 8]);
                const bf16x8 blo = *reinterpret_cast<const bf16x8*>(&Wp[16384 + ((s * 8 + c) * 64 + lane) * 8]);
                acc[c] = __builtin_amdgcn_mfma_f32_16x16x32_bf16(ahi, bhi, acc[c], 0, 0, 0);
                acc[c] = __builtin_amdgcn_mfma_f32_16x16x32_bf16(ahi, blo, acc[c], 0, 0, 0);
            }
        }
    }

    const int node0 = r0 + 16 * wave + ((lane >> 4) << 2);
    const int fc = lane & 15;
#pragma unroll
    for (int c = 0; c < 8; c++) {
        const float bb = bias[c * 16 + fc];
#pragma unroll
        for (int reg = 0; reg < 4; reg++) {
            const int node = node0 + reg;
            if (node < nrows)
                C[((long)c * N_NODES + node) * 16 + fc] = acc[c][reg] + bb;
        }
    }
}

// ---------------- GCN gather: bf16 rows in -> bf16 rows out; unroll x4 ----------
// wave = 2 nodes x 32 lanes; lane l handles features l*4..l*4+3.

__global__ void gather_gcn(const ushort* __restrict__ hb, const int* __restrict__ rowptr,
                           const int2* __restrict__ csr, const float* __restrict__ dinv,
                           const float* __restrict__ bias, ushort* __restrict__ outB) {
    const int tid = threadIdx.x;
    const int d = blockIdx.x * 8 + (tid >> 5);
    if (d >= N_NODES) return;
    const int l = tid & 31;
    const float di = dinv[d];
    const int beg = rowptr[d];
    const int end = rowptr[d + 1];
    float a0 = 0.f, a1 = 0.f, a2 = 0.f, a3 = 0.f;
    int j = beg;
    for (; j + 4 <= end; j += 4) {
        const int4 cA = *reinterpret_cast<const int4*>(&csr[j]);      // e0, e1
        const int4 cB = *reinterpret_cast<const int4*>(&csr[j + 2]);  // e2, e3
        const float n0 = __int_as_float(cA.y);
        const float n1 = __int_as_float(cA.w);
        const float n2 = __int_as_float(cB.y);
        const float n3 = __int_as_float(cB.w);
        const ushort4 u0 = *reinterpret_cast<const ushort4*>(hb + (long)cA.x * HIDDEN + l * 4);
        const ushort4 u1 = *reinterpret_cast<const ushort4*>(hb + (long)cA.z * HIDDEN + l * 4);
        const ushort4 u2 = *reinterpret_cast<const ushort4*>(hb + (long)cB.x * HIDDEN + l * 4);
        const ushort4 u3 = *reinterpret_cast<const ushort4*>(hb + (long)cB.z * HIDDEN + l * 4);
        a0 += bf2f(u0.x) * n0 + bf2f(u1.x) * n1 + bf2f(u2.x) * n2 + bf2f(u3.x) * n3;
        a1 += bf2f(u0.y) * n0 + bf2f(u1.y) * n1 + bf2f(u2.y) * n2 + bf2f(u3.y) * n3;
        a2 += bf2f(u0.z) * n0 + bf2f(u1.z) * n1 + bf2f(u2.z) * n2 + bf2f(u3.z) * n3;
        a3 += bf2f(u0.w) * n0 + bf2f(u1.w) * n1 + bf2f(u2.w) * n2 + bf2f(u3.w) * n3;
    }
    for (; j < end; j++) {
        const int2 e0 = csr[j];
        const float n0 = __int_as_float(e0.y);
        const ushort4 u0 = *reinterpret_cast<const ushort4*>(hb + (long)e0.x * HIDDEN + l * 4);
        a0 += bf2f(u0.x) * n0;
        a1 += bf2f(u0.y) * n0;
        a2 += bf2f(u0.z) * n0;
        a3 += bf2f(u0.w) * n0;
    }
    const ushort4 us = *reinterpret_cast<const ushort4*>(hb + (long)d * HIDDEN + l * 4);
    const float4 b = *reinterpret_cast<const float4*>(bias + l * 4);
    const float invdeg = di * di;
    ushort4 o;
    o.x = f2bf(fmaxf(a0 + bf2f(us.x) * invdeg + b.x, 0.f));
    o.y = f2bf(fmaxf(a1 + bf2f(us.y) * invdeg + b.y, 0.f));
    o.z = f2bf(fmaxf(a2 + bf2f(us.z) * invdeg + b.z, 0.f));
    o.w = f2bf(fmaxf(a3 + bf2f(us.w) * invdeg + b.w, 0.f));
    *reinterpret_cast<ushort4*>(outB + (long)d * HIDDEN + l * 4) = o;
}

// ---------------- SAGE mean gather: bf16 rows in -> bf16 rows out; unroll x4 ----

__global__ void gather_sage(const ushort* __restrict__ hb, const int* __restrict__ rowptr,
                            const int2* __restrict__ csr, ushort* __restrict__ mean) {
    const int tid = threadIdx.x;
    const int d = blockIdx.x * 8 + (tid >> 5);
    if (d >= N_NODES) return;
    const int l = tid & 31;
    const int beg = rowptr[d];
    const int end = rowptr[d + 1];
    float a0 = 0.f, a1 = 0.f, a2 = 0.f, a3 = 0.f;
    int j = beg;
    for (; j + 4 <= end; j += 4) {
        const int4 cA = *reinterpret_cast<const int4*>(&csr[j]);
        const int4 cB = *reinterpret_cast<const int4*>(&csr[j + 2]);
        const ushort4 u0 = *reinterpret_cast<const ushort4*>(hb + (long)cA.x * HIDDEN + l * 4);
        const ushort4 u1 = *reinterpret_cast<const ushort4*>(hb + (long)cA.z * HIDDEN + l * 4);
        const ushort4 u2 = *reinterpret_cast<const ushort4*>(hb + (long)cB.x * HIDDEN + l * 4);
        const ushort4 u3 = *reinterpret_cast<const ushort4*>(hb + (long)cB.z * HIDDEN + l * 4);
        a0 += bf2f(u0.x) + bf2f(u1.x) + bf2f(u2.x) + bf2f(u3.x);
        a1 += bf2f(u0.y) + bf2f(u1.y) + bf2f(u2.y) + bf2f(u3.y);
        a2 += bf2f(u0.z) + bf2f(u1.z) + bf2f(u2.z) + bf2f(u3.z);
        a3 += bf2f(u0.w) + bf2f(u1.w) + bf2f(u2.w) + bf2f(u3.w);
    }
    for (; j < end; j++) {
        const int2 e0 = csr[j];
        const ushort4 u0 = *reinterpret_cast<const ushort4*>(hb + (long)e0.x * HIDDEN + l * 4);
        a0 += bf2f(u0.x);
        a1 += bf2f(u0.y);
        a2 += bf2f(u0.z);
        a3 += bf2f(u0.w);
    }
    const float inv = 1.0f / fmaxf((float)(end - beg), 1.0f);
    ushort4 o;
    o.x = f2bf(a0 * inv); o.y = f2bf(a1 * inv);
    o.z = f2bf(a2 * inv); o.w = f2bf(a3 * inv);
    *reinterpret_cast<ushort4*>(mean + (long)d * HIDDEN + l * 4) = o;
}

// ---------------- pooling (two-stage; batch sorted; fp32 chunked input) ---------

__device__ int lower_bound_batch(const int* __restrict__ batch, int key) {
    int lo = 0, hi = N_NODES;
    while (lo < hi) {
        int mid = (lo + hi) >> 1;
        if (batch[mid] < key) lo = mid + 1;
        else hi = mid;
    }
    return lo;
}

__global__ void pool_partial(const float* __restrict__ node, const int* __restrict__ batch,
                             float* __restrict__ part) {
    const int b = blockIdx.x;          // g * SLICES + k
    const int g = b / SLICES;
    const int k = b % SLICES;
    const int t = threadIdx.x;         // feature t
    const long cbase = (long)(t >> 4) * N_NODES;
    const int foff = t & 15;
    const int lo = lower_bound_batch(batch, g);
    const int hi = lower_bound_batch(batch, g + 1);
    const int len = hi - lo;
    const int per = (len + SLICES - 1) / SLICES;
    const int s = lo + k * per;
    const int e = min(s + per, hi);
    float acc = 0.f;
    for (int i = s; i < e; i++) acc += node[(cbase + i) * 16 + foff];
    part[(long)b * HIDDEN + t] = acc;
}

__global__ void pool_reduce(const float* __restrict__ part, const int* __restrict__ batch,
                            float* __restrict__ out) {
    const int g = blockIdx.x;
    const int t = threadIdx.x;
    float acc = 0.f;
#pragma unroll
    for (int k = 0; k < SLICES; k++) acc += part[(long)(g * SLICES + k) * HIDDEN + t];
    const int lo = lower_bound_batch(batch, g);
    const int hi = lower_bound_batch(batch, g + 1);
    out[g * HIDDEN + t] = acc / fmaxf((float)(hi - lo), 1.0f);
}

// ---------------- launch ----------------

extern "C" void kernel_launch(void* const* d_in, const int* in_sizes, int n_in,
                              void* d_out, int out_size, void* d_ws, size_t ws_size,
                              hipStream_t stream) {
    const float* x    = (const float*)d_in[0];
    const int*   ei   = (const int*)d_in[1];   // [2][E]
    const int*   batch= (const int*)d_in[2];
    const float* W1   = (const float*)d_in[3];
    const float* b1   = (const float*)d_in[4];
    const float* W2   = (const float*)d_in[5];
    const float* b2   = (const float*)d_in[6];
    const float* W_l  = (const float*)d_in[7];
    const float* W_r  = (const float*)d_in[8];
    const float* b_s  = (const float*)d_in[9];
    float* out = (float*)d_out;

    const int* src = ei;
    const int* dst = ei + N_EDGES;

    // workspace layout (deg & fillcnt ADJACENT -> one memset)
    char* ws = (char*)d_ws;
    const size_t NB = (size_t)N_NODES * HIDDEN * sizeof(float);    // 25.6 MB
    const size_t HB = (size_t)N_NODES * HIDDEN * sizeof(ushort);   // 12.8 MB
    float*  SOUT = (float*)(ws);                 // fp32 chunked (sage out, pool in)
    ushort* HP   = (ushort*)(ws + NB);           // bf16 rows: gemm1/2 out
    ushort* G1   = (ushort*)(ws + NB + HB);      // bf16 rows: gather1 out
    ushort* G2   = (ushort*)(ws + 2 * NB);       // bf16 rows: gather2 out
    ushort* MEAN = (ushort*)(ws + 2 * NB + HB);  // bf16 rows: sage mean
    size_t off = 3 * NB;
    int*   deg      = (int*)(ws + off);   off += (size_t)N_NODES * 4;
    int*   fillcnt  = (int*)(ws + off);   off += (size_t)N_NODES * 4;
    float* dinv     = (float*)(ws + off); off += (size_t)N_NODES * 4;
    int*   rowptr   = (int*)(ws + off);   off += (size_t)(N_NODES + 1) * 4;
    int2*  csr      = (int2*)(ws + off);  off += (size_t)N_EDGES * 8;
    float* part     = (float*)(ws + off); off += (size_t)N_GRAPHS * SLICES * HIDDEN * 4;
    int*   bsum     = (int*)(ws + off);   off += (size_t)SCAN_B * 4;
    int*   boff     = (int*)(ws + off);   off += (size_t)SCAN_B * 4;
    ushort* wpack   = (ushort*)(ws + off); off += (size_t)4 * 32768 * 2;

    const ushort* Wp1 = wpack;                // W1
    const ushort* Wp2 = wpack + 32768;        // W2
    const ushort* WpL = wpack + 2 * 32768;    // W_l
    const ushort* WpR = wpack + 3 * 32768;    // W_r

    const int EB = (N_EDGES + 255) / 256;
    const int GB = (N_NODES + 63) / 64;   // 64-row MFMA tiles (782)
    const int GTB = (N_NODES + 7) / 8;    // gather blocks (8 nodes/block)

    // ---- pack weights (bf16 hi/lo, fragment order) ----
    pack_w<<<32, 256, 0, stream>>>(W1, W2, W_l, W_r, wpack);

    // ---- build CSR (once per call) ----
    hipMemsetAsync(deg, 0, (size_t)N_NODES * 8, stream);  // deg + fillcnt
    deg_kernel<<<EB, 256, 0, stream>>>(dst, deg);
    scan_partial<<<SCAN_B, 256, 0, stream>>>(deg, bsum);
    scan_bsum<<<1, 256, 0, stream>>>(bsum, boff, rowptr);
    scan_final<<<SCAN_B, 256, 0, stream>>>(deg, boff, rowptr, dinv);
    fill_kernel<<<EB, 256, 0, stream>>>(src, dst, rowptr, fillcnt, dinv, csr);

    // ---- GCN layer 1 ----
    gemm_f32in<<<GB, 256, 0, stream>>>(x, Wp1, HP, N_NODES);
    gather_gcn<<<GTB, 256, 0, stream>>>(HP, rowptr, csr, dinv, b1, G1);

    // ---- GCN layer 2 ----
    gemm_bf16in<<<GB, 256, 0, stream>>>(G1, Wp2, HP, N_NODES);
    gather_gcn<<<GTB, 256, 0, stream>>>(HP, rowptr, csr, dinv, b2, G2);

    // ---- SAGE ----
    gather_sage<<<GTB, 256, 0, stream>>>(G2, rowptr, csr, MEAN);
    gemm_sage_bf16in<<<GB, 256, 0, stream>>>(MEAN, WpL, G2, WpR, b_s, SOUT, N_NODES);

    // ---- global mean pool (two-stage, no atomics) ----
    pool_partial<<<N_GRAPHS * SLICES, 128, 0, stream>>>(SOUT, batch, part);
    pool_reduce<<<N_GRAPHS, 128, 0, stream>>>(part, batch, out);
}

// Round 21
// 244.211 us; speedup vs baseline: 1.7292x; 1.0029x over previous
//
#include <hip/hip_runtime.h>

#define N_NODES 50000
#define N_EDGES 600000
#define HIDDEN 128
#define N_GRAPHS 64
#define SLICES 16
#define SCAN_B ((N_NODES + 255) / 256)   // 196

typedef __attribute__((ext_vector_type(8))) short bf16x8;
typedef __attribute__((ext_vector_type(4))) float f32x4;

__device__ inline ushort f2bf(float v) {
    union { float f; unsigned u; } x; x.f = v;
    unsigned r = (x.u + 0x7FFF + ((x.u >> 16) & 1)) >> 16;  // RNE
    return (ushort)r;
}
__device__ inline float bf2f(ushort h) {
    union { unsigned u; float f; } x; x.u = ((unsigned)h) << 16;
    return x.f;
}

// Inter-kernel node features: bf16 ROW-MAJOR (256B rows).

// ---------------- degree ----------------

__global__ void deg_kernel(const int* __restrict__ dst, int* __restrict__ deg) {
    int t = blockIdx.x * 256 + threadIdx.x;
    if (t < N_EDGES) atomicAdd(&deg[dst[t]], 1);
}

// ---------------- 3-pass parallel scan: deg -> rowptr (+ fused dinv) ----------------

__global__ void scan_partial(const int* __restrict__ deg, int* __restrict__ bsum) {
    const int b = blockIdx.x, t = threadIdx.x;
    const int i = b * 256 + t;
    int v = (i < N_NODES) ? deg[i] : 0;
    __shared__ int wsum[4];
#pragma unroll
    for (int o = 32; o > 0; o >>= 1) v += __shfl_down(v, o, 64);
    if ((t & 63) == 0) wsum[t >> 6] = v;
    __syncthreads();
    if (t == 0) bsum[b] = wsum[0] + wsum[1] + wsum[2] + wsum[3];
}

__global__ void scan_bsum(const int* __restrict__ bsum, int* __restrict__ boff,
                          int* __restrict__ rowptr) {
    __shared__ int s[256];
    const int t = threadIdx.x;
    const int v = (t < SCAN_B) ? bsum[t] : 0;
    s[t] = v;
    __syncthreads();
    for (int o = 1; o < 256; o <<= 1) {
        int u = (t >= o) ? s[t - o] : 0;
        __syncthreads();
        s[t] += u;
        __syncthreads();
    }
    if (t < SCAN_B) boff[t] = s[t] - v;      // exclusive
    if (t == 255) rowptr[N_NODES] = s[255];  // total == N_EDGES
}

__global__ void scan_final(const int* __restrict__ deg, const int* __restrict__ boff,
                           int* __restrict__ rowptr, float* __restrict__ dinv) {
    const int b = blockIdx.x, t = threadIdx.x;
    const int i = b * 256 + t;
    __shared__ int s[256];
    const int v = (i < N_NODES) ? deg[i] : 0;
    s[t] = v;
    __syncthreads();
    for (int o = 1; o < 256; o <<= 1) {
        int u = (t >= o) ? s[t - o] : 0;
        __syncthreads();
        s[t] += u;
        __syncthreads();
    }
    if (i < N_NODES) {
        rowptr[i] = boff[b] + s[t] - v;
        dinv[i] = rsqrtf((float)v + 1.0f);
    }
}

// ---------------- CSR fill: interleaved {src, norm} ----------------

__global__ void fill_kernel(const int* __restrict__ src, const int* __restrict__ dst,
                            const int* __restrict__ rowptr, int* __restrict__ fillcnt,
                            const float* __restrict__ dinv, int2* __restrict__ csr) {
    int e = blockIdx.x * 256 + threadIdx.x;
    if (e >= N_EDGES) return;
    const int d = dst[e];
    const int s = src[e];
    const int pos = rowptr[d] + atomicAdd(&fillcnt[d], 1);
    csr[pos] = make_int2(s, __float_as_int(dinv[s] * dinv[d]));
}

// ---------------- W pack: fp32 [128k][128n] -> bf16 hi/lo in MFMA fragment order --

__global__ void pack_w(const float* __restrict__ Wa, const float* __restrict__ Wb,
                       const float* __restrict__ Wc, const float* __restrict__ Wd,
                       ushort* __restrict__ out) {
    const int m = blockIdx.x >> 3;
    const int gid = (blockIdx.x & 7) * 256 + threadIdx.x;  // 0..2047
    const float* W = (m == 0) ? Wa : (m == 1) ? Wb : (m == 2) ? Wc : Wd;
    const int s = gid >> 9;
    const int c = (gid >> 6) & 7;
    const int lane = gid & 63;
    const int kbase = s * 32 + 8 * (lane >> 4);
    const int n = c * 16 + (lane & 15);
    ushort* hi = out + (long)m * 32768;
    ushort* lo = hi + 16384;
#pragma unroll
    for (int j = 0; j < 8; j++) {
        const float v = W[(kbase + j) * HIDDEN + n];
        const ushort h = f2bf(v);
        hi[gid * 8 + j] = h;
        lo[gid * 8 + j] = f2bf(v - bf2f(h));
    }
}

// ---------------- GEMM1: fp32 row-major A (= x) @ W -> bf16 rows; bf16x3 --------

__global__ void gemm_f32in(const float* __restrict__ A, const ushort* __restrict__ Wp,
                           ushort* __restrict__ Cb, int nrows) {
    __shared__ alignas(16) ushort Ah[64 * 128];
    __shared__ alignas(16) ushort Al[64 * 128];
    const int r0 = blockIdx.x * 64;
    const int tid = threadIdx.x;

#pragma unroll
    for (int i = 0; i < 8; i++) {
        const int idx = tid + i * 256;          // 0..2047 float4 slots
        const int node = idx >> 5;              // 0..63
        const int f0 = 4 * (idx & 31);
        float4 v = make_float4(0.f, 0.f, 0.f, 0.f);
        if (r0 + node < nrows)
            v = reinterpret_cast<const float4*>(A + (long)r0 * HIDDEN)[idx];
        const ushort h0 = f2bf(v.x), h1 = f2bf(v.y), h2 = f2bf(v.z), h3 = f2bf(v.w);
        ushort4 h4; h4.x = h0; h4.y = h1; h4.z = h2; h4.w = h3;
        ushort4 l4;
        l4.x = f2bf(v.x - bf2f(h0)); l4.y = f2bf(v.y - bf2f(h1));
        l4.z = f2bf(v.z - bf2f(h2)); l4.w = f2bf(v.w - bf2f(h3));
        const int kb = (2 * f0) ^ ((node & 7) << 4);
        *reinterpret_cast<ushort4*>(&Ah[(node * 256 + kb) >> 1]) = h4;
        *reinterpret_cast<ushort4*>(&Al[(node * 256 + kb) >> 1]) = l4;
    }
    __syncthreads();

    const int wave = tid >> 6;
    const int lane = tid & 63;
    const int arow = 16 * wave + (lane & 15);

    f32x4 acc[8];
#pragma unroll
    for (int c = 0; c < 8; c++) acc[c] = (f32x4){0.f, 0.f, 0.f, 0.f};

#pragma unroll
    for (int s = 0; s < 4; s++) {
        const int koff = (s * 64 + ((lane >> 4) << 4)) ^ ((arow & 7) << 4);
        const bf16x8 ahi = *reinterpret_cast<const bf16x8*>(&Ah[(arow * 256 + koff) >> 1]);
        const bf16x8 alo = *reinterpret_cast<const bf16x8*>(&Al[(arow * 256 + koff) >> 1]);
#pragma unroll
        for (int c = 0; c < 8; c++) {
            const bf16x8 bhi = *reinterpret_cast<const bf16x8*>(&Wp[((s * 8 + c) * 64 + lane) * 8]);
            const bf16x8 blo = *reinterpret_cast<const bf16x8*>(&Wp[16384 + ((s * 8 + c) * 64 + lane) * 8]);
            acc[c] = __builtin_amdgcn_mfma_f32_16x16x32_bf16(ahi, bhi, acc[c], 0, 0, 0);
            acc[c] = __builtin_amdgcn_mfma_f32_16x16x32_bf16(alo, bhi, acc[c], 0, 0, 0);
            acc[c] = __builtin_amdgcn_mfma_f32_16x16x32_bf16(ahi, blo, acc[c], 0, 0, 0);
        }
    }

    const int node0 = r0 + 16 * wave + ((lane >> 4) << 2);
    const int fc = lane & 15;
#pragma unroll
    for (int c = 0; c < 8; c++) {
#pragma unroll
        for (int reg = 0; reg < 4; reg++) {
            const int node = node0 + reg;
            if (node < nrows)
                Cb[(long)node * HIDDEN + c * 16 + fc] = f2bf(acc[c][reg]);
        }
    }
}

// ---------------- bf16-input staging helper (16 KB LDS, XOR swizzle) ------------

__device__ inline void stage_bf16(const ushort* __restrict__ Ab, ushort* __restrict__ Ah,
                                  int r0, int tid, int nrows) {
#pragma unroll
    for (int i = 0; i < 4; i++) {
        const int idx = tid + i * 256;          // 0..1023 bf16x8 slots
        const int node = idx >> 4;              // 0..63
        const int g = idx & 15;                 // 16B group
        bf16x8 v = (bf16x8){0, 0, 0, 0, 0, 0, 0, 0};
        if (r0 + node < nrows)
            v = *reinterpret_cast<const bf16x8*>(Ab + (long)(r0 + node) * HIDDEN + g * 8);
        const int kb = (g * 16) ^ ((node & 7) << 4);
        *reinterpret_cast<bf16x8*>(&Ah[(node * 256 + kb) >> 1]) = v;
    }
}

// ---------------- GEMM2: bf16 rows A @ W -> bf16 rows; 2-term MFMA --------------

__global__ void gemm_bf16in(const ushort* __restrict__ Ab, const ushort* __restrict__ Wp,
                            ushort* __restrict__ Cb, int nrows) {
    __shared__ alignas(16) ushort Ah[64 * 128];
    const int r0 = blockIdx.x * 64;
    const int tid = threadIdx.x;

    stage_bf16(Ab, Ah, r0, tid, nrows);
    __syncthreads();

    const int wave = tid >> 6;
    const int lane = tid & 63;
    const int arow = 16 * wave + (lane & 15);

    f32x4 acc[8];
#pragma unroll
    for (int c = 0; c < 8; c++) acc[c] = (f32x4){0.f, 0.f, 0.f, 0.f};

#pragma unroll
    for (int s = 0; s < 4; s++) {
        const int koff = (s * 64 + ((lane >> 4) << 4)) ^ ((arow & 7) << 4);
        const bf16x8 ahi = *reinterpret_cast<const bf16x8*>(&Ah[(arow * 256 + koff) >> 1]);
#pragma unroll
        for (int c = 0; c < 8; c++) {
            const bf16x8 bhi = *reinterpret_cast<const bf16x8*>(&Wp[((s * 8 + c) * 64 + lane) * 8]);
            const bf16x8 blo = *reinterpret_cast<const bf16x8*>(&Wp[16384 + ((s * 8 + c) * 64 + lane) * 8]);
            acc[c] = __builtin_amdgcn_mfma_f32_16x16x32_bf16(ahi, bhi, acc[c], 0, 0, 0);
            acc[c] = __builtin_amdgcn_mfma_f32_16x16x32_bf16(ahi, blo, acc[c], 0, 0, 0);
        }
    }

    const int node0 = r0 + 16 * wave + ((lane >> 4) << 2);
    const int fc = lane & 15;
#pragma unroll
    for (int c = 0; c < 8; c++) {
#pragma unroll
        for (int reg = 0; reg < 4; reg++) {
            const int node = node0 + reg;
            if (node < nrows)
                Cb[(long)node * HIDDEN + c * 16 + fc] = f2bf(acc[c][reg]);
        }
    }
}

// ---------------- SAGE GEMM: bf16 A1@Wl + bf16 A2@Wr + b -> bf16 rows -----------

__global__ void gemm_sage_bf16in(const ushort* __restrict__ A1, const ushort* __restrict__ Wp1,
                                 const ushort* __restrict__ A2, const ushort* __restrict__ Wp2,
                                 const float* __restrict__ bias, ushort* __restrict__ Cb,
                                 int nrows) {
    __shared__ alignas(16) ushort Ah[64 * 128];
    const int r0 = blockIdx.x * 64;
    const int tid = threadIdx.x;
    const int wave = tid >> 6;
    const int lane = tid & 63;
    const int arow = 16 * wave + (lane & 15);

    f32x4 acc[8];
#pragma unroll
    for (int c = 0; c < 8; c++) acc[c] = (f32x4){0.f, 0.f, 0.f, 0.f};

    for (int p = 0; p < 2; p++) {
        const ushort* Ab = (p == 0) ? A1 : A2;
        const ushort* Wp = (p == 0) ? Wp1 : Wp2;
        if (p) __syncthreads();
        stage_bf16(Ab, Ah, r0, tid, nrows);
        __syncthreads();

#pragma unroll
        for (int s = 0; s < 4; s++) {
            const int koff = (s * 64 + ((lane >> 4) << 4)) ^ ((arow & 7) << 4);
            const bf16x8 ahi = *reinterpret_cast<const bf16x8*>(&Ah[(arow * 256 + koff) >> 1]);
#pragma unroll
            for (int c = 0; c < 8; c++) {
                const bf16x8 bhi = *reinterpret_cast<const bf16x8*>(&Wp[((s * 8 + c) * 64 + lane) * 8]);
                const bf16x8 blo = *reinterpret_cast<const bf16x8*>(&Wp[16384 + ((s * 8 + c) * 64 + lane) * 8]);
                acc[c] = __builtin_amdgcn_mfma_f32_16x16x32_bf16(ahi, bhi, acc[c], 0, 0, 0);
                acc[c] = __builtin_amdgcn_mfma_f32_16x16x32_bf16(ahi, blo, acc[c], 0, 0, 0);
            }
        }
    }

    const int node0 = r0 + 16 * wave + ((lane >> 4) << 2);
    const int fc = lane & 15;
#pragma unroll
    for (int c = 0; c < 8; c++) {
        const float bb = bias[c * 16 + fc];
#pragma unroll
        for (int reg = 0; reg < 4; reg++) {
            const int node = node0 + reg;
            if (node < nrows)
                Cb[(long)node * HIDDEN + c * 16 + fc] = f2bf(acc[c][reg] + bb);
        }
    }
}

// ---------------- GCN gather: bf16 rows in -> bf16 rows out; unroll x4 ----------
// wave = 2 nodes x 32 lanes; lane l handles features l*4..l*4+3.

__global__ void gather_gcn(const ushort* __restrict__ hb, const int* __restrict__ rowptr,
                           const int2* __restrict__ csr, const float* __restrict__ dinv,
                           const float* __restrict__ bias, ushort* __restrict__ outB) {
    const int tid = threadIdx.x;
    const int d = blockIdx.x * 8 + (tid >> 5);
    if (d >= N_NODES) return;
    const int l = tid & 31;
    const float di = dinv[d];
    const int beg = rowptr[d];
    const int end = rowptr[d + 1];
    float a0 = 0.f, a1 = 0.f, a2 = 0.f, a3 = 0.f;
    int j = beg;
    for (; j + 4 <= end; j += 4) {
        const int4 cA = *reinterpret_cast<const int4*>(&csr[j]);      // e0, e1
        const int4 cB = *reinterpret_cast<const int4*>(&csr[j + 2]);  // e2, e3
        const float n0 = __int_as_float(cA.y);
        const float n1 = __int_as_float(cA.w);
        const float n2 = __int_as_float(cB.y);
        const float n3 = __int_as_float(cB.w);
        const ushort4 u0 = *reinterpret_cast<const ushort4*>(hb + (long)cA.x * HIDDEN + l * 4);
        const ushort4 u1 = *reinterpret_cast<const ushort4*>(hb + (long)cA.z * HIDDEN + l * 4);
        const ushort4 u2 = *reinterpret_cast<const ushort4*>(hb + (long)cB.x * HIDDEN + l * 4);
        const ushort4 u3 = *reinterpret_cast<const ushort4*>(hb + (long)cB.z * HIDDEN + l * 4);
        a0 += bf2f(u0.x) * n0 + bf2f(u1.x) * n1 + bf2f(u2.x) * n2 + bf2f(u3.x) * n3;
        a1 += bf2f(u0.y) * n0 + bf2f(u1.y) * n1 + bf2f(u2.y) * n2 + bf2f(u3.y) * n3;
        a2 += bf2f(u0.z) * n0 + bf2f(u1.z) * n1 + bf2f(u2.z) * n2 + bf2f(u3.z) * n3;
        a3 += bf2f(u0.w) * n0 + bf2f(u1.w) * n1 + bf2f(u2.w) * n2 + bf2f(u3.w) * n3;
    }
    for (; j < end; j++) {
        const int2 e0 = csr[j];
        const float n0 = __int_as_float(e0.y);
        const ushort4 u0 = *reinterpret_cast<const ushort4*>(hb + (long)e0.x * HIDDEN + l * 4);
        a0 += bf2f(u0.x) * n0;
        a1 += bf2f(u0.y) * n0;
        a2 += bf2f(u0.z) * n0;
        a3 += bf2f(u0.w) * n0;
    }
    const ushort4 us = *reinterpret_cast<const ushort4*>(hb + (long)d * HIDDEN + l * 4);
    const float4 b = *reinterpret_cast<const float4*>(bias + l * 4);
    const float invdeg = di * di;
    ushort4 o;
    o.x = f2bf(fmaxf(a0 + bf2f(us.x) * invdeg + b.x, 0.f));
    o.y = f2bf(fmaxf(a1 + bf2f(us.y) * invdeg + b.y, 0.f));
    o.z = f2bf(fmaxf(a2 + bf2f(us.z) * invdeg + b.z, 0.f));
    o.w = f2bf(fmaxf(a3 + bf2f(us.w) * invdeg + b.w, 0.f));
    *reinterpret_cast<ushort4*>(outB + (long)d * HIDDEN + l * 4) = o;
}

// ---------------- SAGE mean gather: bf16 rows in -> bf16 rows out; unroll x4 ----

__global__ void gather_sage(const ushort* __restrict__ hb, const int* __restrict__ rowptr,
                            const int2* __restrict__ csr, ushort* __restrict__ mean) {
    const int tid = threadIdx.x;
    const int d = blockIdx.x * 8 + (tid >> 5);
    if (d >= N_NODES) return;
    const int l = tid & 31;
    const int beg = rowptr[d];
    const int end = rowptr[d + 1];
    float a0 = 0.f, a1 = 0.f, a2 = 0.f, a3 = 0.f;
    int j = beg;
    for (; j + 4 <= end; j += 4) {
        const int4 cA = *reinterpret_cast<const int4*>(&csr[j]);
        const int4 cB = *reinterpret_cast<const int4*>(&csr[j + 2]);
        const ushort4 u0 = *reinterpret_cast<const ushort4*>(hb + (long)cA.x * HIDDEN + l * 4);
        const ushort4 u1 = *reinterpret_cast<const ushort4*>(hb + (long)cA.z * HIDDEN + l * 4);
        const ushort4 u2 = *reinterpret_cast<const ushort4*>(hb + (long)cB.x * HIDDEN + l * 4);
        const ushort4 u3 = *reinterpret_cast<const ushort4*>(hb + (long)cB.z * HIDDEN + l * 4);
        a0 += bf2f(u0.x) + bf2f(u1.x) + bf2f(u2.x) + bf2f(u3.x);
        a1 += bf2f(u0.y) + bf2f(u1.y) + bf2f(u2.y) + bf2f(u3.y);
        a2 += bf2f(u0.z) + bf2f(u1.z) + bf2f(u2.z) + bf2f(u3.z);
        a3 += bf2f(u0.w) + bf2f(u1.w) + bf2f(u2.w) + bf2f(u3.w);
    }
    for (; j < end; j++) {
        const int2 e0 = csr[j];
        const ushort4 u0 = *reinterpret_cast<const ushort4*>(hb + (long)e0.x * HIDDEN + l * 4);
        a0 += bf2f(u0.x);
        a1 += bf2f(u0.y);
        a2 += bf2f(u0.z);
        a3 += bf2f(u0.w);
    }
    const float inv = 1.0f / fmaxf((float)(end - beg), 1.0f);
    ushort4 o;
    o.x = f2bf(a0 * inv); o.y = f2bf(a1 * inv);
    o.z = f2bf(a2 * inv); o.w = f2bf(a3 * inv);
    *reinterpret_cast<ushort4*>(mean + (long)d * HIDDEN + l * 4) = o;
}

// ---------------- pooling (two-stage; batch sorted; bf16 row input) -------------

__device__ int lower_bound_batch(const int* __restrict__ batch, int key) {
    int lo = 0, hi = N_NODES;
    while (lo < hi) {
        int mid = (lo + hi) >> 1;
        if (batch[mid] < key) lo = mid + 1;
        else hi = mid;
    }
    return lo;
}

__global__ void pool_partial(const ushort* __restrict__ node, const int* __restrict__ batch,
                             float* __restrict__ part) {
    const int b = blockIdx.x;          // g * SLICES + k
    const int g = b / SLICES;
    const int k = b % SLICES;
    const int t = threadIdx.x;         // feature t (128 thr, 2B each = 256B row)
    const int lo = lower_bound_batch(batch, g);
    const int hi = lower_bound_batch(batch, g + 1);
    const int len = hi - lo;
    const int per = (len + SLICES - 1) / SLICES;
    const int s = lo + k * per;
    const int e = min(s + per, hi);
    float acc = 0.f;
    for (int i = s; i < e; i++) acc += bf2f(node[(long)i * HIDDEN + t]);
    part[(long)b * HIDDEN + t] = acc;
}

__global__ void pool_reduce(const float* __restrict__ part, const int* __restrict__ batch,
                            float* __restrict__ out) {
    const int g = blockIdx.x;
    const int t = threadIdx.x;
    float acc = 0.f;
#pragma unroll
    for (int k = 0; k < SLICES; k++) acc += part[(long)(g * SLICES + k) * HIDDEN + t];
    const int lo = lower_bound_batch(batch, g);
    const int hi = lower_bound_batch(batch, g + 1);
    out[g * HIDDEN + t] = acc / fmaxf((float)(hi - lo), 1.0f);
}

// ---------------- launch ----------------

extern "C" void kernel_launch(void* const* d_in, const int* in_sizes, int n_in,
                              void* d_out, int out_size, void* d_ws, size_t ws_size,
                              hipStream_t stream) {
    const float* x    = (const float*)d_in[0];
    const int*   ei   = (const int*)d_in[1];   // [2][E]
    const int*   batch= (const int*)d_in[2];
    const float* W1   = (const float*)d_in[3];
    const float* b1   = (const float*)d_in[4];
    const float* W2   = (const float*)d_in[5];
    const float* b2   = (const float*)d_in[6];
    const float* W_l  = (const float*)d_in[7];
    const float* W_r  = (const float*)d_in[8];
    const float* b_s  = (const float*)d_in[9];
    float* out = (float*)d_out;

    const int* src = ei;
    const int* dst = ei + N_EDGES;

    // workspace layout (deg & fillcnt ADJACENT -> one memset)
    char* ws = (char*)d_ws;
    const size_t HB = (size_t)N_NODES * HIDDEN * sizeof(ushort);   // 12.8 MB
    ushort* HP   = (ushort*)(ws);                // bf16 rows: gemm1/2 out
    ushort* G1   = (ushort*)(ws + HB);           // bf16 rows: gather1 out
    ushort* G2   = (ushort*)(ws + 2 * HB);       // bf16 rows: gather2 out
    ushort* MEAN = (ushort*)(ws + 3 * HB);       // bf16 rows: sage mean
    ushort* SOUT = (ushort*)(ws + 4 * HB);       // bf16 rows: sage gemm out
    size_t off = 5 * HB;
    int*   deg      = (int*)(ws + off);   off += (size_t)N_NODES * 4;
    int*   fillcnt  = (int*)(ws + off);   off += (size_t)N_NODES * 4;
    float* dinv     = (float*)(ws + off); off += (size_t)N_NODES * 4;
    int*   rowptr   = (int*)(ws + off);   off += (size_t)(N_NODES + 1) * 4;
    int2*  csr      = (int2*)(ws + off);  off += (size_t)N_EDGES * 8;
    float* part     = (float*)(ws + off); off += (size_t)N_GRAPHS * SLICES * HIDDEN * 4;
    int*   bsum     = (int*)(ws + off);   off += (size_t)SCAN_B * 4;
    int*   boff     = (int*)(ws + off);   off += (size_t)SCAN_B * 4;
    ushort* wpack   = (ushort*)(ws + off); off += (size_t)4 * 32768 * 2;

    const ushort* Wp1 = wpack;                // W1
    const ushort* Wp2 = wpack + 32768;        // W2
    const ushort* WpL = wpack + 2 * 32768;    // W_l
    const ushort* WpR = wpack + 3 * 32768;    // W_r

    const int EB = (N_EDGES + 255) / 256;
    const int GB = (N_NODES + 63) / 64;   // 64-row MFMA tiles (782)
    const int GTB = (N_NODES + 7) / 8;    // gather blocks (8 nodes/block)

    // ---- pack weights (bf16 hi/lo, fragment order) ----
    pack_w<<<32, 256, 0, stream>>>(W1, W2, W_l, W_r, wpack);

    // ---- build CSR (once per call) ----
    hipMemsetAsync(deg, 0, (size_t)N_NODES * 8, stream);  // deg + fillcnt
    deg_kernel<<<EB, 256, 0, stream>>>(dst, deg);
    scan_partial<<<SCAN_B, 256, 0, stream>>>(deg, bsum);
    scan_bsum<<<1, 256, 0, stream>>>(bsum, boff, rowptr);
    scan_final<<<SCAN_B, 256, 0, stream>>>(deg, boff, rowptr, dinv);
    fill_kernel<<<EB, 256, 0, stream>>>(src, dst, rowptr, fillcnt, dinv, csr);

    // ---- GCN layer 1 ----
    gemm_f32in<<<GB, 256, 0, stream>>>(x, Wp1, HP, N_NODES);
    gather_gcn<<<GTB, 256, 0, stream>>>(HP, rowptr, csr, dinv, b1, G1);

    // ---- GCN layer 2 ----
    gemm_bf16in<<<GB, 256, 0, stream>>>(G1, Wp2, HP, N_NODES);
    gather_gcn<<<GTB, 256, 0, stream>>>(HP, rowptr, csr, dinv, b2, G2);

    // ---- SAGE ----
    gather_sage<<<GTB, 256, 0, stream>>>(G2, rowptr, csr, MEAN);
    gemm_sage_bf16in<<<GB, 256, 0, stream>>>(MEAN, WpL, G2, WpR, b_s, SOUT, N_NODES);

    // ---- global mean pool (two-stage, no atomics) ----
    pool_partial<<<N_GRAPHS * SLICES, 128, 0, stream>>>(SOUT, batch, part);
    pool_reduce<<<N_GRAPHS, 128, 0, stream>>>(part, batch, out);
}